// Round 2
// baseline (5028.707 us; speedup 1.0000x reference)
//
#include <hip/hip_runtime.h>
#include <math.h>

#define NEGS 0.2f

__device__ __forceinline__ unsigned fenc(float f) {
  unsigned b = __float_as_uint(f);
  return (b & 0x80000000u) ? ~b : (b | 0x80000000u);
}
__device__ __forceinline__ float fdec(unsigned k) {
  return __uint_as_float((k & 0x80000000u) ? (k & 0x7fffffffu) : ~k);
}

// ---------------- GEMM1: C[M,64] = A[M,K] @ B[K,64], K % 100 == 0 ----------
__global__ __launch_bounds__(256) void k_gemm1(const float* __restrict__ A,
                                               const float* __restrict__ B,
                                               float* __restrict__ C,
                                               int M, int K) {
  __shared__ float As[64][100];
  __shared__ float Bs[100][64];
  const int tid = threadIdx.x;
  const int row0 = blockIdx.x * 64;
  const int tr = tid >> 4;   // 0..15 -> row group of 4
  const int tc = tid & 15;   // 0..15 -> col group of 4
  float acc[4][4] = {};
  for (int k0 = 0; k0 < K; k0 += 100) {
    for (int i = tid; i < 6400; i += 256) {
      int m = i / 100, k = i - m * 100;
      int gr = row0 + m;
      As[m][k] = (gr < M) ? A[(size_t)gr * K + k0 + k] : 0.f;
    }
    for (int i = tid; i < 6400; i += 256) {
      int k = i >> 6, c = i & 63;
      Bs[k][c] = B[(size_t)(k0 + k) * 64 + c];
    }
    __syncthreads();
#pragma unroll 5
    for (int kk = 0; kk < 100; ++kk) {
      float4 b4 = *(const float4*)&Bs[kk][tc * 4];
      float a[4];
#pragma unroll
      for (int r = 0; r < 4; ++r) a[r] = As[tr * 4 + r][kk];
#pragma unroll
      for (int r = 0; r < 4; ++r) {
        acc[r][0] += a[r] * b4.x;
        acc[r][1] += a[r] * b4.y;
        acc[r][2] += a[r] * b4.z;
        acc[r][3] += a[r] * b4.w;
      }
    }
    __syncthreads();
  }
#pragma unroll
  for (int r = 0; r < 4; ++r) {
    int gr = row0 + tr * 4 + r;
    if (gr < M) {
      float4 o = make_float4(acc[r][0], acc[r][1], acc[r][2], acc[r][3]);
      *(float4*)&C[(size_t)gr * 64 + tc * 4] = o;
    }
  }
}

// ---------------- layer-1 prep: attention halves + zero init ---------------
__global__ void k_prep1(const float* __restrict__ xw,
                        const float* __restrict__ asr,
                        const float* __restrict__ adt,
                        float* __restrict__ ssrc, float* __restrict__ sdst,
                        unsigned* __restrict__ menc, float* __restrict__ denom,
                        float* __restrict__ out1, int Nn) {
  int idx = blockIdx.x * blockDim.x + threadIdx.x;
  if (idx >= Nn * 8) return;
  int h = idx & 7;
  const float* xr = xw + (size_t)(idx >> 3) * 64 + h * 8;
  float ss = 0.f, sd = 0.f;
#pragma unroll
  for (int c = 0; c < 8; ++c) {
    float v = xr[c];
    ss += v * asr[h * 8 + c];
    sd += v * adt[h * 8 + c];
  }
  ssrc[idx] = ss;
  sdst[idx] = sd;
  menc[idx] = 0u;
  denom[idx] = 0.f;
  float* o = out1 + (size_t)(idx >> 3) * 64 + h * 8;
#pragma unroll
  for (int c = 0; c < 8; ++c) o[c] = 0.f;
}

// ---------------- layer-1 edge pass A: segment max --------------------------
__global__ void k_emax1(const int* __restrict__ ei,
                        const float* __restrict__ ssrc,
                        const float* __restrict__ sdst,
                        unsigned* __restrict__ menc, int E, int Etot) {
  int idx = blockIdx.x * blockDim.x + threadIdx.x;
  if (idx >= Etot * 8) return;
  int h = idx & 7;
  int e = idx >> 3;
  int s, d;
  if (e < E) { s = ei[e]; d = ei[E + e]; }
  else       { s = d = e - E; }
  float v = ssrc[s * 8 + h] + sdst[d * 8 + h];
  v = v > 0.f ? v : NEGS * v;
  atomicMax(&menc[d * 8 + h], fenc(v));
}

// ---------------- layer-1 edge pass B: exp + weighted scatter ---------------
__global__ void k_eaggr1(const int* __restrict__ ei,
                         const float* __restrict__ ssrc,
                         const float* __restrict__ sdst,
                         const unsigned* __restrict__ menc,
                         const float* __restrict__ xw,
                         float* __restrict__ denom, float* __restrict__ out1,
                         int E, int Etot) {
  int idx = blockIdx.x * blockDim.x + threadIdx.x;
  if (idx >= Etot * 8) return;
  int h = idx & 7;
  int e = idx >> 3;
  int s, d;
  if (e < E) { s = ei[e]; d = ei[E + e]; }
  else       { s = d = e - E; }
  float v = ssrc[s * 8 + h] + sdst[d * 8 + h];
  v = v > 0.f ? v : NEGS * v;
  float p = expf(v - fdec(menc[d * 8 + h]));
  atomicAdd(&denom[d * 8 + h], p);
  const float* xs = xw + (size_t)s * 64 + h * 8;
  float* od = out1 + (size_t)d * 64 + h * 8;
#pragma unroll
  for (int c = 0; c < 8; ++c) atomicAdd(&od[c], p * xs[c]);
}

// ---------------- layer-1 finalize: normalize + bias + elu ------------------
__global__ void k_fin1(float* __restrict__ h1, const float* __restrict__ denom,
                       const float* __restrict__ b1, int Nn) {
  int idx = blockIdx.x * blockDim.x + threadIdx.x;
  if (idx >= Nn * 64) return;
  int n = idx >> 6, hc = idx & 63;
  float v = h1[idx] / denom[n * 8 + (hc >> 3)] + b1[hc];
  h1[idx] = v > 0.f ? v : (expf(v) - 1.f);
}

// ---------------- GEMM2: xw2[N,16] = h1[N,64] @ W2[64,16] -------------------
__global__ __launch_bounds__(256) void k_gemm2(const float* __restrict__ h1,
                                               const float* __restrict__ W2,
                                               float* __restrict__ xw2, int Nn) {
  __shared__ float w[64 * 16];
  int tid = threadIdx.x;
  for (int i = tid; i < 1024; i += 256) w[i] = W2[i];
  __syncthreads();
  int idx = blockIdx.x * 256 + tid;
  if (idx >= Nn * 16) return;
  int n = idx >> 4, c = idx & 15;
  const float* hr = h1 + (size_t)n * 64;
  float acc = 0.f;
#pragma unroll 8
  for (int k = 0; k < 64; ++k) acc += hr[k] * w[k * 16 + c];
  xw2[idx] = acc;
}

// ---------------- layer-2 prep ----------------------------------------------
__global__ void k_prep2(const float* __restrict__ xw2,
                        const float* __restrict__ asr,
                        const float* __restrict__ adt,
                        float* __restrict__ ssrc, float* __restrict__ sdst,
                        unsigned* __restrict__ menc, float* __restrict__ denom,
                        float* __restrict__ out2, int Nn) {
  int n = blockIdx.x * blockDim.x + threadIdx.x;
  if (n >= Nn) return;
  const float* xr = xw2 + (size_t)n * 16;
  float ss = 0.f, sd = 0.f;
#pragma unroll
  for (int c = 0; c < 16; ++c) {
    float v = xr[c];
    ss += v * asr[c];
    sd += v * adt[c];
  }
  ssrc[n] = ss;
  sdst[n] = sd;
  menc[n] = 0u;
  denom[n] = 0.f;
  float* o = out2 + (size_t)n * 16;
#pragma unroll
  for (int c = 0; c < 16; ++c) o[c] = 0.f;
}

// ---------------- layer-2 edge pass A ----------------------------------------
__global__ void k_emax2(const int* __restrict__ ei,
                        const float* __restrict__ ssrc,
                        const float* __restrict__ sdst,
                        unsigned* __restrict__ menc, int E, int Etot) {
  int e = blockIdx.x * blockDim.x + threadIdx.x;
  if (e >= Etot) return;
  int s, d;
  if (e < E) { s = ei[e]; d = ei[E + e]; }
  else       { s = d = e - E; }
  float v = ssrc[s] + sdst[d];
  v = v > 0.f ? v : NEGS * v;
  atomicMax(&menc[d], fenc(v));
}

// ---------------- layer-2 edge pass B ----------------------------------------
__global__ void k_eaggr2(const int* __restrict__ ei,
                         const float* __restrict__ ssrc,
                         const float* __restrict__ sdst,
                         const unsigned* __restrict__ menc,
                         const float* __restrict__ xw2,
                         float* __restrict__ denom, float* __restrict__ out2,
                         int E, int Etot) {
  int e = blockIdx.x * blockDim.x + threadIdx.x;
  if (e >= Etot) return;
  int s, d;
  if (e < E) { s = ei[e]; d = ei[E + e]; }
  else       { s = d = e - E; }
  float v = ssrc[s] + sdst[d];
  v = v > 0.f ? v : NEGS * v;
  float p = expf(v - fdec(menc[d]));
  atomicAdd(&denom[d], p);
  const float* xs = xw2 + (size_t)s * 16;
  float* od = out2 + (size_t)d * 16;
#pragma unroll
  for (int c = 0; c < 16; ++c) atomicAdd(&od[c], p * xs[c]);
}

// ---------------- layer-2 finalize: normalize + bias + log_softmax ----------
__global__ void k_fin2(float* __restrict__ out, const float* __restrict__ denom,
                       const float* __restrict__ b2, int Nn) {
  int n = blockIdx.x * blockDim.x + threadIdx.x;
  if (n >= Nn) return;
  float inv = 1.f / denom[n];
  float v[16];
  float mx = -1e30f;
#pragma unroll
  for (int c = 0; c < 16; ++c) {
    v[c] = out[(size_t)n * 16 + c] * inv + b2[c];
    mx = fmaxf(mx, v[c]);
  }
  float s = 0.f;
#pragma unroll
  for (int c = 0; c < 16; ++c) s += expf(v[c] - mx);
  float lse = logf(s);
#pragma unroll
  for (int c = 0; c < 16; ++c) out[(size_t)n * 16 + c] = v[c] - mx - lse;
}

extern "C" void kernel_launch(void* const* d_in, const int* in_sizes, int n_in,
                              void* d_out, int out_size, void* d_ws, size_t ws_size,
                              hipStream_t stream) {
  const float* x      = (const float*)d_in[0];
  const int* ei       = (const int*)d_in[1];   // harness converts int inputs to int32
  const float* W1     = (const float*)d_in[2];
  const float* a_src1 = (const float*)d_in[3];
  const float* a_dst1 = (const float*)d_in[4];
  const float* b1     = (const float*)d_in[5];
  const float* W2     = (const float*)d_in[6];
  const float* a_src2 = (const float*)d_in[7];
  const float* a_dst2 = (const float*)d_in[8];
  const float* b2     = (const float*)d_in[9];

  const int F    = in_sizes[2] / 64;   // 500
  const int Nn   = in_sizes[0] / F;    // 100000
  const int E    = in_sizes[1] / 2;    // 1600000
  const int Etot = E + Nn;             // + self loops

  // workspace layout (floats); layer-2 buffers reuse the xw1 region
  float* ws = (float*)d_ws;
  float* xw1      = ws;                              // Nn*64
  float* ssrc1    = xw1 + (size_t)Nn * 64;           // Nn*8
  float* sdst1    = ssrc1 + (size_t)Nn * 8;          // Nn*8
  unsigned* menc1 = (unsigned*)(sdst1 + (size_t)Nn * 8);   // Nn*8
  float* denom1   = (float*)menc1 + (size_t)Nn * 8;  // Nn*8
  float* h1       = denom1 + (size_t)Nn * 8;         // Nn*64 (accum, then elu in place)

  float* xw2      = ws;                              // Nn*16 (xw1 dead by then)
  float* ssrc2    = xw2 + (size_t)Nn * 16;           // Nn
  float* sdst2    = ssrc2 + Nn;                      // Nn
  unsigned* menc2 = (unsigned*)(sdst2 + Nn);         // Nn
  float* denom2   = (float*)menc2 + Nn;              // Nn
  float* out2     = (float*)d_out;                   // Nn*16

  dim3 blk(256);

  // ---- layer 1 ----
  k_gemm1<<<dim3((Nn + 63) / 64), blk, 0, stream>>>(x, W1, xw1, Nn, F);
  k_prep1<<<dim3((Nn * 8 + 255) / 256), blk, 0, stream>>>(
      xw1, a_src1, a_dst1, ssrc1, sdst1, menc1, denom1, h1, Nn);
  k_emax1<<<dim3(((size_t)Etot * 8 + 255) / 256), blk, 0, stream>>>(
      ei, ssrc1, sdst1, menc1, E, Etot);
  k_eaggr1<<<dim3(((size_t)Etot * 8 + 255) / 256), blk, 0, stream>>>(
      ei, ssrc1, sdst1, menc1, xw1, denom1, h1, E, Etot);
  k_fin1<<<dim3((Nn * 64 + 255) / 256), blk, 0, stream>>>(h1, denom1, b1, Nn);

  // ---- layer 2 ----
  k_gemm2<<<dim3((Nn * 16 + 255) / 256), blk, 0, stream>>>(h1, W2, xw2, Nn);
  k_prep2<<<dim3((Nn + 255) / 256), blk, 0, stream>>>(
      xw2, a_src2, a_dst2, ssrc2, sdst2, menc2, denom2, out2, Nn);
  k_emax2<<<dim3((Etot + 255) / 256), blk, 0, stream>>>(
      ei, ssrc2, sdst2, menc2, E, Etot);
  k_eaggr2<<<dim3((Etot + 255) / 256), blk, 0, stream>>>(
      ei, ssrc2, sdst2, menc2, xw2, denom2, out2, E, Etot);
  k_fin2<<<dim3((Nn + 255) / 256), blk, 0, stream>>>(out2, denom2, b2, Nn);
}

// Round 3
// 819.190 us; speedup vs baseline: 6.1386x; 6.1386x over previous
//
#include <hip/hip_runtime.h>
#include <math.h>

#define NEGS 0.2f
#define SCAN_CHUNK 2048   // 256 threads x 8 elements

// ---------------- GEMM1: C[M,64] = A[M,K] @ B[K,64], K % 100 == 0 ----------
__global__ __launch_bounds__(256) void k_gemm1(const float* __restrict__ A,
                                               const float* __restrict__ B,
                                               float* __restrict__ C,
                                               int M, int K) {
  __shared__ float As[64][100];
  __shared__ float Bs[100][64];
  const int tid = threadIdx.x;
  const int row0 = blockIdx.x * 64;
  const int tr = tid >> 4;
  const int tc = tid & 15;
  float acc[4][4] = {};
  for (int k0 = 0; k0 < K; k0 += 100) {
    for (int i = tid; i < 6400; i += 256) {
      int m = i / 100, k = i - m * 100;
      int gr = row0 + m;
      As[m][k] = (gr < M) ? A[(size_t)gr * K + k0 + k] : 0.f;
    }
    for (int i = tid; i < 6400; i += 256) {
      int k = i >> 6, c = i & 63;
      Bs[k][c] = B[(size_t)(k0 + k) * 64 + c];
    }
    __syncthreads();
#pragma unroll 5
    for (int kk = 0; kk < 100; ++kk) {
      float4 b4 = *(const float4*)&Bs[kk][tc * 4];
      float a[4];
#pragma unroll
      for (int r = 0; r < 4; ++r) a[r] = As[tr * 4 + r][kk];
#pragma unroll
      for (int r = 0; r < 4; ++r) {
        acc[r][0] += a[r] * b4.x;
        acc[r][1] += a[r] * b4.y;
        acc[r][2] += a[r] * b4.z;
        acc[r][3] += a[r] * b4.w;
      }
    }
    __syncthreads();
  }
#pragma unroll
  for (int r = 0; r < 4; ++r) {
    int gr = row0 + tr * 4 + r;
    if (gr < M) {
      float4 o = make_float4(acc[r][0], acc[r][1], acc[r][2], acc[r][3]);
      *(float4*)&C[(size_t)gr * 64 + tc * 4] = o;
    }
  }
}

// ---------------- CSR build: histogram -> scan -> scatter -------------------
__global__ void k_ones(int* __restrict__ cnt, int Nn) {
  int i = blockIdx.x * blockDim.x + threadIdx.x;
  if (i < Nn) cnt[i] = 1;   // self-loop
}

__global__ void k_hist(const int* __restrict__ ei, int* __restrict__ cnt, int E) {
  int e = blockIdx.x * blockDim.x + threadIdx.x;
  if (e < E) atomicAdd(&cnt[ei[E + e]], 1);
}

// block-level scan: each block handles SCAN_CHUNK elements
__global__ __launch_bounds__(256) void k_scan1(const int* __restrict__ cnt,
                                               int* __restrict__ pre,
                                               int* __restrict__ part, int Nn) {
  __shared__ int sh[256];
  const int t = threadIdx.x;
  const int base = blockIdx.x * SCAN_CHUNK + t * 8;
  int e[8];
  int ts = 0;
#pragma unroll
  for (int j = 0; j < 8; ++j) {
    int idx = base + j;
    e[j] = (idx < Nn) ? cnt[idx] : 0;
    ts += e[j];
  }
  sh[t] = ts;
  __syncthreads();
  for (int off = 1; off < 256; off <<= 1) {
    int v = (t >= off) ? sh[t - off] : 0;
    __syncthreads();
    sh[t] += v;
    __syncthreads();
  }
  int excl = sh[t] - ts;
  int w = 0;
#pragma unroll
  for (int j = 0; j < 8; ++j) {
    int idx = base + j;
    if (idx < Nn) pre[idx] = excl + w;
    w += e[j];
  }
  if (t == 255) part[blockIdx.x] = sh[255];
}

__global__ void k_scan2(int* __restrict__ part, int nb,
                        int* __restrict__ rowptr, int Nn) {
  if (blockIdx.x == 0 && threadIdx.x == 0) {
    int run = 0;
    for (int b = 0; b < nb; ++b) {
      int v = part[b];
      part[b] = run;
      run += v;
    }
    rowptr[Nn] = run;
  }
}

__global__ void k_scan3(const int* __restrict__ pre, const int* __restrict__ part,
                        int* __restrict__ rowptr, int* __restrict__ cursor, int Nn) {
  int i = blockIdx.x * blockDim.x + threadIdx.x;
  if (i >= Nn) return;
  int v = pre[i] + part[i / SCAN_CHUNK];
  rowptr[i] = v;
  cursor[i] = v;
}

__global__ void k_fillcsr(const int* __restrict__ ei, int* __restrict__ cursor,
                          int* __restrict__ col, int E, int Etot) {
  int e = blockIdx.x * blockDim.x + threadIdx.x;
  if (e >= Etot) return;
  int s, d;
  if (e < E) { s = ei[e]; d = ei[E + e]; }
  else       { s = d = e - E; }
  int pos = atomicAdd(&cursor[d], 1);
  col[pos] = s;
}

// ---------------- layer-1 prep: attention halves ----------------------------
__global__ void k_prep1(const float* __restrict__ xw,
                        const float* __restrict__ asr,
                        const float* __restrict__ adt,
                        float* __restrict__ ssrc, float* __restrict__ sdst,
                        int Nn) {
  int idx = blockIdx.x * blockDim.x + threadIdx.x;
  if (idx >= Nn * 8) return;
  int h = idx & 7;
  const float* xr = xw + (size_t)(idx >> 3) * 64 + h * 8;
  float ss = 0.f, sd = 0.f;
#pragma unroll
  for (int c = 0; c < 8; ++c) {
    float v = xr[c];
    ss += v * asr[h * 8 + c];
    sd += v * adt[h * 8 + c];
  }
  ssrc[idx] = ss;
  sdst[idx] = sd;
}

// ---------------- layer-1 aggregate: one wave per dst node ------------------
// lane = h*8+c; fused softmax-normalize + bias + ELU
__global__ __launch_bounds__(256) void k_agg1(const int* __restrict__ rowptr,
                                              const int* __restrict__ col,
                                              const float* __restrict__ ssrc,
                                              const float* __restrict__ sdst,
                                              const float* __restrict__ xw,
                                              const float* __restrict__ b1,
                                              float* __restrict__ h1, int Nn) {
  int wid = (blockIdx.x * 256 + threadIdx.x) >> 6;
  if (wid >= Nn) return;
  int lane = threadIdx.x & 63;
  int h = lane >> 3;
  float sd = sdst[wid * 8 + h];
  int start = rowptr[wid], end = rowptr[wid + 1];
  float m = -1e30f;
  for (int i = start; i < end; ++i) {
    int s = col[i];
    float v = ssrc[s * 8 + h] + sd;
    v = v > 0.f ? v : NEGS * v;
    m = fmaxf(m, v);
  }
  float den = 0.f, acc = 0.f;
  for (int i = start; i < end; ++i) {
    int s = col[i];
    float v = ssrc[s * 8 + h] + sd;
    v = v > 0.f ? v : NEGS * v;
    float p = expf(v - m);
    den += p;
    acc += p * xw[(size_t)s * 64 + lane];
  }
  float o = acc / den + b1[lane];
  h1[(size_t)wid * 64 + lane] = o > 0.f ? o : (expf(o) - 1.f);
}

// ---------------- GEMM2: xw2[N,16] = h1[N,64] @ W2[64,16] -------------------
__global__ __launch_bounds__(256) void k_gemm2(const float* __restrict__ h1,
                                               const float* __restrict__ W2,
                                               float* __restrict__ xw2, int Nn) {
  __shared__ float w[64 * 16];
  int tid = threadIdx.x;
  for (int i = tid; i < 1024; i += 256) w[i] = W2[i];
  __syncthreads();
  int idx = blockIdx.x * 256 + tid;
  if (idx >= Nn * 16) return;
  int n = idx >> 4, c = idx & 15;
  const float* hr = h1 + (size_t)n * 64;
  float acc = 0.f;
#pragma unroll 8
  for (int k = 0; k < 64; ++k) acc += hr[k] * w[k * 16 + c];
  xw2[idx] = acc;
}

// ---------------- layer-2 prep ----------------------------------------------
__global__ void k_prep2(const float* __restrict__ xw2,
                        const float* __restrict__ asr,
                        const float* __restrict__ adt,
                        float* __restrict__ ssrc, float* __restrict__ sdst,
                        int Nn) {
  int n = blockIdx.x * blockDim.x + threadIdx.x;
  if (n >= Nn) return;
  const float* xr = xw2 + (size_t)n * 16;
  float ss = 0.f, sd = 0.f;
#pragma unroll
  for (int c = 0; c < 16; ++c) {
    float v = xr[c];
    ss += v * asr[c];
    sd += v * adt[c];
  }
  ssrc[n] = ss;
  sdst[n] = sd;
}

// ---------------- layer-2 aggregate: one wave per dst node ------------------
// lane = slot*16 + c (4 edge slots x 16 channels); fused bias + log_softmax
__global__ __launch_bounds__(256) void k_agg2(const int* __restrict__ rowptr,
                                              const int* __restrict__ col,
                                              const float* __restrict__ ssrc,
                                              const float* __restrict__ sdst,
                                              const float* __restrict__ xw2,
                                              const float* __restrict__ b2,
                                              float* __restrict__ out, int Nn) {
  int wid = (blockIdx.x * 256 + threadIdx.x) >> 6;
  if (wid >= Nn) return;
  int lane = threadIdx.x & 63;
  int slot = lane >> 4, c = lane & 15;
  float sd = sdst[wid];
  int start = rowptr[wid], end = rowptr[wid + 1];
  float m = -1e30f;
  for (int i = start + slot; i < end; i += 4) {
    int s = col[i];
    float v = ssrc[s] + sd;
    v = v > 0.f ? v : NEGS * v;
    m = fmaxf(m, v);
  }
  m = fmaxf(m, __shfl_xor(m, 16));
  m = fmaxf(m, __shfl_xor(m, 32));
  float den = 0.f, acc = 0.f;
  for (int i = start + slot; i < end; i += 4) {
    int s = col[i];
    float v = ssrc[s] + sd;
    v = v > 0.f ? v : NEGS * v;
    float p = expf(v - m);
    den += p;
    acc += p * xw2[(size_t)s * 16 + c];
  }
  den += __shfl_xor(den, 16);
  den += __shfl_xor(den, 32);
  acc += __shfl_xor(acc, 16);
  acc += __shfl_xor(acc, 32);
  float o = acc / den + b2[c];
  // log-softmax over the 16 channels (each 16-lane group holds all 16)
  float mx = o;
#pragma unroll
  for (int off = 1; off < 16; off <<= 1) mx = fmaxf(mx, __shfl_xor(mx, off));
  float ex = expf(o - mx);
  float ssum = ex;
#pragma unroll
  for (int off = 1; off < 16; off <<= 1) ssum += __shfl_xor(ssum, off);
  float r = o - mx - logf(ssum);
  if (slot == 0) out[(size_t)wid * 16 + c] = r;
}

extern "C" void kernel_launch(void* const* d_in, const int* in_sizes, int n_in,
                              void* d_out, int out_size, void* d_ws, size_t ws_size,
                              hipStream_t stream) {
  const float* x      = (const float*)d_in[0];
  const int* ei       = (const int*)d_in[1];
  const float* W1     = (const float*)d_in[2];
  const float* a_src1 = (const float*)d_in[3];
  const float* a_dst1 = (const float*)d_in[4];
  const float* b1     = (const float*)d_in[5];
  const float* W2     = (const float*)d_in[6];
  const float* a_src2 = (const float*)d_in[7];
  const float* a_dst2 = (const float*)d_in[8];
  const float* b2     = (const float*)d_in[9];

  const int F    = in_sizes[2] / 64;   // 500
  const int Nn   = in_sizes[0] / F;    // 100000
  const int E    = in_sizes[1] / 2;    // 1600000
  const int Etot = E + Nn;
  const int nb   = (Nn + SCAN_CHUNK - 1) / SCAN_CHUNK;

  // ---- workspace layout (4-byte units) ----
  float* ws = (float*)d_ws;
  float* xw1    = ws;                               // Nn*64
  float* h1     = xw1 + (size_t)Nn * 64;            // Nn*64
  float* ssrc1  = h1 + (size_t)Nn * 64;             // Nn*8
  float* sdst1  = ssrc1 + (size_t)Nn * 8;           // Nn*8
  int* cnt      = (int*)(sdst1 + (size_t)Nn * 8);   // Nn (histogram, then pre)
  int* pre      = cnt + Nn;                         // Nn
  int* rowptr   = pre + Nn;                         // Nn+1
  int* cursor   = rowptr + Nn + 1;                  // Nn
  int* part     = cursor + Nn;                      // nb (+pad)
  int* col      = part + 256;                       // Etot
  // layer-2 buffers reuse xw1 region (dead after k_agg1)
  float* xw2    = xw1;                              // Nn*16
  float* ssrc2  = xw2 + (size_t)Nn * 16;            // Nn
  float* sdst2  = ssrc2 + Nn;                       // Nn
  float* out2   = (float*)d_out;                    // Nn*16

  dim3 blk(256);

  // ---- CSR build (shared by both layers) ----
  k_ones<<<dim3((Nn + 255) / 256), blk, 0, stream>>>(cnt, Nn);
  k_hist<<<dim3((E + 255) / 256), blk, 0, stream>>>(ei, cnt, E);
  k_scan1<<<dim3(nb), blk, 0, stream>>>(cnt, pre, part, Nn);
  k_scan2<<<dim3(1), blk, 0, stream>>>(part, nb, rowptr, Nn);
  k_scan3<<<dim3((Nn + 255) / 256), blk, 0, stream>>>(pre, part, rowptr, cursor, Nn);
  k_fillcsr<<<dim3((Etot + 255) / 256), blk, 0, stream>>>(ei, cursor, col, E, Etot);

  // ---- layer 1 ----
  k_gemm1<<<dim3((Nn + 63) / 64), blk, 0, stream>>>(x, W1, xw1, Nn, F);
  k_prep1<<<dim3((Nn * 8 + 255) / 256), blk, 0, stream>>>(
      xw1, a_src1, a_dst1, ssrc1, sdst1, Nn);
  k_agg1<<<dim3((Nn * 64 + 255) / 256), blk, 0, stream>>>(
      rowptr, col, ssrc1, sdst1, xw1, b1, h1, Nn);

  // ---- layer 2 ----
  k_gemm2<<<dim3((Nn * 16 + 255) / 256), blk, 0, stream>>>(h1, W2, xw2, Nn);
  k_prep2<<<dim3((Nn + 255) / 256), blk, 0, stream>>>(
      xw2, a_src2, a_dst2, ssrc2, sdst2, Nn);
  k_agg2<<<dim3((Nn * 64 + 255) / 256), blk, 0, stream>>>(
      rowptr, col, ssrc2, sdst2, xw2, b2, out2, Nn);
}

// Round 4
// 628.450 us; speedup vs baseline: 8.0018x; 1.3035x over previous
//
#include <hip/hip_runtime.h>
#include <math.h>

#define NEGS 0.2f
#define SCAN_CHUNK 2048   // 256 threads x 8 elements

typedef __attribute__((ext_vector_type(8))) short bf16x8;
typedef __attribute__((ext_vector_type(4))) float f32x4;

__device__ __forceinline__ unsigned short f2bf(float f) {
  unsigned u = __float_as_uint(f);
  u += 0x7fffu + ((u >> 16) & 1);   // RNE
  return (unsigned short)(u >> 16);
}

// ---------------- W1 -> bf16, transposed [col][k], K padded, XOR-swizzled ---
// Output layout: chunk ck (64 k each): byte = ck*8192 + ((c*128 + kk*2) ^ ((c&7)<<4))
__global__ void k_wcvt(const float* __restrict__ W1, unsigned short* __restrict__ Wb,
                       int K, int nthr) {
  int t = blockIdx.x * blockDim.x + threadIdx.x;
  if (t >= nthr) return;
  int c = t & 63;
  int g = t >> 6;            // k-group of 4
  int kgl0 = g * 4;
  int ck = kgl0 >> 6;
  int kk0 = kgl0 & 63;
  unsigned short h[4];
#pragma unroll
  for (int j = 0; j < 4; ++j) {
    int kg = kgl0 + j;
    float f = (kg < K) ? W1[(size_t)kg * 64 + c] : 0.f;
    h[j] = f2bf(f);
  }
  size_t byte = (size_t)ck * 8192 + (unsigned)((c * 128 + kk0 * 2) ^ ((c & 7) << 4));
  ushort4 v = make_ushort4(h[0], h[1], h[2], h[3]);
  *(ushort4*)((char*)Wb + byte) = v;
}

// ---------------- GEMM1 (MFMA bf16): C[M,64] = A[M,K] @ W1[K,64] ------------
__global__ __launch_bounds__(256) void k_gemm1m(const float* __restrict__ A,
                                                const unsigned short* __restrict__ Wb,
                                                float* __restrict__ C,
                                                int M, int K, int nck) {
  __shared__ __align__(16) char smem[16384 + 8192];
  char* Al = smem;           // 128 rows x 128 B (bf16, swizzled)
  char* Bl = smem + 16384;   // 64 cols x 128 B (bf16, swizzled; one chunk)
  const int tid = threadIdx.x;
  const int lane = tid & 63;
  const int wid = tid >> 6;
  const int wr = wid >> 1, wc = wid & 1;
  const int bm = blockIdx.x * 128;
  const int srow = tid >> 2;     // 0..63 (pass adds 64)
  const int sq = tid & 3;        // 16-k quarter

  f32x4 acc[4][2] = {};

  for (int ck = 0; ck < nck; ++ck) {
    // ---- B stage: linear copy of pre-swizzled chunk (8 KB) ----
    {
      const uint4* gs = (const uint4*)((const char*)Wb + (size_t)ck * 8192);
      uint4* ld = (uint4*)Bl;
      ld[tid * 2]     = gs[tid * 2];
      ld[tid * 2 + 1] = gs[tid * 2 + 1];
    }
    // ---- A stage: f32 global -> bf16 -> swizzled LDS ----
#pragma unroll
    for (int p = 0; p < 2; ++p) {
      int r = srow + p * 64;
      int grow = bm + r;
      int kbase = ck * 64 + sq * 16;
      float f[16];
      if (grow < M && kbase + 16 <= K) {
        const float4* g = (const float4*)(A + (size_t)grow * K + kbase);
        float4 v0 = g[0], v1 = g[1], v2 = g[2], v3 = g[3];
        f[0]=v0.x; f[1]=v0.y; f[2]=v0.z; f[3]=v0.w;
        f[4]=v1.x; f[5]=v1.y; f[6]=v1.z; f[7]=v1.w;
        f[8]=v2.x; f[9]=v2.y; f[10]=v2.z; f[11]=v2.w;
        f[12]=v3.x; f[13]=v3.y; f[14]=v3.z; f[15]=v3.w;
      } else {
#pragma unroll
        for (int j = 0; j < 16; ++j) {
          int kg = kbase + j;
          f[j] = (grow < M && kg < K) ? A[(size_t)grow * K + kg] : 0.f;
        }
      }
      unsigned pk[8];
#pragma unroll
      for (int j = 0; j < 8; ++j)
        pk[j] = (unsigned)f2bf(f[2 * j]) | ((unsigned)f2bf(f[2 * j + 1]) << 16);
      unsigned xr = (unsigned)((r & 7) << 4);
      uint4 lo = make_uint4(pk[0], pk[1], pk[2], pk[3]);
      uint4 hi = make_uint4(pk[4], pk[5], pk[6], pk[7]);
      *(uint4*)(Al + r * 128 + ((sq * 32) ^ xr))      = lo;
      *(uint4*)(Al + r * 128 + ((sq * 32 + 16) ^ xr)) = hi;
    }
    __syncthreads();
    // ---- MFMA: 2 k-steps of 32 ----
    const int kgrp = lane >> 4;
    const int r15 = lane & 15;
#pragma unroll
    for (int ks = 0; ks < 2; ++ks) {
      bf16x8 a[4], b[2];
#pragma unroll
      for (int mr = 0; mr < 4; ++mr) {
        int row = wr * 64 + mr * 16 + r15;
        a[mr] = *(const bf16x8*)(Al + row * 128 +
                 ((ks * 64 + kgrp * 16) ^ ((row & 7) << 4)));
      }
#pragma unroll
      for (int nc = 0; nc < 2; ++nc) {
        int col = wc * 32 + nc * 16 + r15;
        b[nc] = *(const bf16x8*)(Bl + col * 128 +
                 ((ks * 64 + kgrp * 16) ^ ((col & 7) << 4)));
      }
#pragma unroll
      for (int mr = 0; mr < 4; ++mr)
#pragma unroll
        for (int nc = 0; nc < 2; ++nc)
          acc[mr][nc] = __builtin_amdgcn_mfma_f32_16x16x32_bf16(
              a[mr], b[nc], acc[mr][nc], 0, 0, 0);
    }
    __syncthreads();
  }
  // ---- store: D col = lane&15, row = (lane>>4)*4 + j ----
  const int r15 = lane & 15;
  const int rg4 = (lane >> 4) * 4;
#pragma unroll
  for (int mr = 0; mr < 4; ++mr) {
#pragma unroll
    for (int nc = 0; nc < 2; ++nc) {
      int row0 = bm + wr * 64 + mr * 16 + rg4;
      int colg = wc * 32 + nc * 16 + r15;
#pragma unroll
      for (int j = 0; j < 4; ++j) {
        int grow = row0 + j;
        if (grow < M) C[(size_t)grow * 64 + colg] = acc[mr][nc][j];
      }
    }
  }
}

// ---------------- CSR build: histogram -> scan -> scatter -------------------
__global__ void k_ones(int* __restrict__ cnt, int Nn) {
  int i = blockIdx.x * blockDim.x + threadIdx.x;
  if (i < Nn) cnt[i] = 1;   // self-loop
}

__global__ void k_hist(const int* __restrict__ ei, int* __restrict__ cnt, int E) {
  int e = blockIdx.x * blockDim.x + threadIdx.x;
  if (e < E) atomicAdd(&cnt[ei[E + e]], 1);
}

__global__ __launch_bounds__(256) void k_scan1(const int* __restrict__ cnt,
                                               int* __restrict__ pre,
                                               int* __restrict__ part, int Nn) {
  __shared__ int sh[256];
  const int t = threadIdx.x;
  const int base = blockIdx.x * SCAN_CHUNK + t * 8;
  int e[8];
  int ts = 0;
#pragma unroll
  for (int j = 0; j < 8; ++j) {
    int idx = base + j;
    e[j] = (idx < Nn) ? cnt[idx] : 0;
    ts += e[j];
  }
  sh[t] = ts;
  __syncthreads();
  for (int off = 1; off < 256; off <<= 1) {
    int v = (t >= off) ? sh[t - off] : 0;
    __syncthreads();
    sh[t] += v;
    __syncthreads();
  }
  int excl = sh[t] - ts;
  int w = 0;
#pragma unroll
  for (int j = 0; j < 8; ++j) {
    int idx = base + j;
    if (idx < Nn) pre[idx] = excl + w;
    w += e[j];
  }
  if (t == 255) part[blockIdx.x] = sh[255];
}

__global__ void k_scan2(int* __restrict__ part, int nb,
                        int* __restrict__ rowptr, int Nn) {
  if (blockIdx.x == 0 && threadIdx.x == 0) {
    int run = 0;
    for (int b = 0; b < nb; ++b) {
      int v = part[b];
      part[b] = run;
      run += v;
    }
    rowptr[Nn] = run;
  }
}

__global__ void k_scan3(const int* __restrict__ pre, const int* __restrict__ part,
                        int* __restrict__ rowptr, int* __restrict__ cursor, int Nn) {
  int i = blockIdx.x * blockDim.x + threadIdx.x;
  if (i >= Nn) return;
  int v = pre[i] + part[i / SCAN_CHUNK];
  rowptr[i] = v;
  cursor[i] = v;
}

__global__ void k_fillcsr(const int* __restrict__ ei, int* __restrict__ cursor,
                          int* __restrict__ col, int E, int Etot) {
  int e = blockIdx.x * blockDim.x + threadIdx.x;
  if (e >= Etot) return;
  int s, d;
  if (e < E) { s = ei[e]; d = ei[E + e]; }
  else       { s = d = e - E; }
  int pos = atomicAdd(&cursor[d], 1);
  col[pos] = s;
}

// ---------------- layer-1 prep: attention halves ----------------------------
__global__ void k_prep1(const float* __restrict__ xw,
                        const float* __restrict__ asr,
                        const float* __restrict__ adt,
                        float* __restrict__ ssrc, float* __restrict__ sdst,
                        int Nn) {
  int idx = blockIdx.x * blockDim.x + threadIdx.x;
  if (idx >= Nn * 8) return;
  int h = idx & 7;
  const float* xr = xw + (size_t)(idx >> 3) * 64 + h * 8;
  float ss = 0.f, sd = 0.f;
#pragma unroll
  for (int c = 0; c < 8; ++c) {
    float v = xr[c];
    ss += v * asr[h * 8 + c];
    sd += v * adt[h * 8 + c];
  }
  ssrc[idx] = ss;
  sdst[idx] = sd;
}

// ---------------- layer-1 aggregate: one wave per dst node ------------------
__global__ __launch_bounds__(256) void k_agg1(const int* __restrict__ rowptr,
                                              const int* __restrict__ col,
                                              const float* __restrict__ ssrc,
                                              const float* __restrict__ sdst,
                                              const float* __restrict__ xw,
                                              const float* __restrict__ b1,
                                              float* __restrict__ h1, int Nn) {
  int wid = (blockIdx.x * 256 + threadIdx.x) >> 6;
  if (wid >= Nn) return;
  int lane = threadIdx.x & 63;
  int h = lane >> 3;
  float sd = sdst[wid * 8 + h];
  int start = rowptr[wid], end = rowptr[wid + 1];
  float m = -1e30f;
  for (int i = start; i < end; ++i) {
    int s = col[i];
    float v = ssrc[s * 8 + h] + sd;
    v = v > 0.f ? v : NEGS * v;
    m = fmaxf(m, v);
  }
  float den = 0.f, acc = 0.f;
  for (int i = start; i < end; ++i) {
    int s = col[i];
    float v = ssrc[s * 8 + h] + sd;
    v = v > 0.f ? v : NEGS * v;
    float p = expf(v - m);
    den += p;
    acc += p * xw[(size_t)s * 64 + lane];
  }
  float o = acc / den + b1[lane];
  h1[(size_t)wid * 64 + lane] = o > 0.f ? o : (expf(o) - 1.f);
}

// ---------------- GEMM2: xw2[N,16] = h1[N,64] @ W2[64,16] -------------------
__global__ __launch_bounds__(256) void k_gemm2(const float* __restrict__ h1,
                                               const float* __restrict__ W2,
                                               float* __restrict__ xw2, int Nn) {
  __shared__ float w[64 * 16];
  int tid = threadIdx.x;
  for (int i = tid; i < 1024; i += 256) w[i] = W2[i];
  __syncthreads();
  int idx = blockIdx.x * 256 + tid;
  if (idx >= Nn * 16) return;
  int n = idx >> 4, c = idx & 15;
  const float* hr = h1 + (size_t)n * 64;
  float acc = 0.f;
#pragma unroll 8
  for (int k = 0; k < 64; ++k) acc += hr[k] * w[k * 16 + c];
  xw2[idx] = acc;
}

// ---------------- layer-2 prep ----------------------------------------------
__global__ void k_prep2(const float* __restrict__ xw2,
                        const float* __restrict__ asr,
                        const float* __restrict__ adt,
                        float* __restrict__ ssrc, float* __restrict__ sdst,
                        int Nn) {
  int n = blockIdx.x * blockDim.x + threadIdx.x;
  if (n >= Nn) return;
  const float* xr = xw2 + (size_t)n * 16;
  float ss = 0.f, sd = 0.f;
#pragma unroll
  for (int c = 0; c < 16; ++c) {
    float v = xr[c];
    ss += v * asr[c];
    sd += v * adt[c];
  }
  ssrc[n] = ss;
  sdst[n] = sd;
}

// ---------------- layer-2 aggregate: one wave per dst node ------------------
__global__ __launch_bounds__(256) void k_agg2(const int* __restrict__ rowptr,
                                              const int* __restrict__ col,
                                              const float* __restrict__ ssrc,
                                              const float* __restrict__ sdst,
                                              const float* __restrict__ xw2,
                                              const float* __restrict__ b2,
                                              float* __restrict__ out, int Nn) {
  int wid = (blockIdx.x * 256 + threadIdx.x) >> 6;
  if (wid >= Nn) return;
  int lane = threadIdx.x & 63;
  int slot = lane >> 4, c = lane & 15;
  float sd = sdst[wid];
  int start = rowptr[wid], end = rowptr[wid + 1];
  float m = -1e30f;
  for (int i = start + slot; i < end; i += 4) {
    int s = col[i];
    float v = ssrc[s] + sd;
    v = v > 0.f ? v : NEGS * v;
    m = fmaxf(m, v);
  }
  m = fmaxf(m, __shfl_xor(m, 16));
  m = fmaxf(m, __shfl_xor(m, 32));
  float den = 0.f, acc = 0.f;
  for (int i = start + slot; i < end; i += 4) {
    int s = col[i];
    float v = ssrc[s] + sd;
    v = v > 0.f ? v : NEGS * v;
    float p = expf(v - m);
    den += p;
    acc += p * xw2[(size_t)s * 16 + c];
  }
  den += __shfl_xor(den, 16);
  den += __shfl_xor(den, 32);
  acc += __shfl_xor(acc, 16);
  acc += __shfl_xor(acc, 32);
  float o = acc / den + b2[c];
  float mx = o;
#pragma unroll
  for (int off = 1; off < 16; off <<= 1) mx = fmaxf(mx, __shfl_xor(mx, off));
  float ex = expf(o - mx);
  float ssum = ex;
#pragma unroll
  for (int off = 1; off < 16; off <<= 1) ssum += __shfl_xor(ssum, off);
  float r = o - mx - logf(ssum);
  if (slot == 0) out[(size_t)wid * 16 + c] = r;
}

extern "C" void kernel_launch(void* const* d_in, const int* in_sizes, int n_in,
                              void* d_out, int out_size, void* d_ws, size_t ws_size,
                              hipStream_t stream) {
  const float* x      = (const float*)d_in[0];
  const int* ei       = (const int*)d_in[1];
  const float* W1     = (const float*)d_in[2];
  const float* a_src1 = (const float*)d_in[3];
  const float* a_dst1 = (const float*)d_in[4];
  const float* b1     = (const float*)d_in[5];
  const float* W2     = (const float*)d_in[6];
  const float* a_src2 = (const float*)d_in[7];
  const float* a_dst2 = (const float*)d_in[8];
  const float* b2     = (const float*)d_in[9];

  const int F    = in_sizes[2] / 64;   // 500
  const int Nn   = in_sizes[0] / F;    // 100000
  const int E    = in_sizes[1] / 2;    // 1600000
  const int Etot = E + Nn;
  const int nb   = (Nn + SCAN_CHUNK - 1) / SCAN_CHUNK;
  const int nck  = (F + 63) >> 6;      // K chunks of 64 (8 for K=500)

  // ---- workspace layout (4-byte units) ----
  float* ws = (float*)d_ws;
  float* xw1    = ws;                               // Nn*64
  float* h1     = xw1 + (size_t)Nn * 64;            // Nn*64
  float* ssrc1  = h1 + (size_t)Nn * 64;             // Nn*8
  float* sdst1  = ssrc1 + (size_t)Nn * 8;           // Nn*8
  int* cnt      = (int*)(sdst1 + (size_t)Nn * 8);   // Nn
  int* pre      = cnt + Nn;                         // Nn
  int* rowptr   = pre + Nn;                         // Nn+1
  int* cursor   = rowptr + Nn + 1;                  // Nn
  int* part     = cursor + Nn;                      // nb (+pad to 256)
  int* col      = part + 256;                       // Etot
  unsigned short* Wb = (unsigned short*)(col + ((Etot + 7) & ~7));  // nck*4096 shorts
  // layer-2 buffers reuse xw1 region (dead after k_agg1)
  float* xw2    = xw1;                              // Nn*16
  float* ssrc2  = xw2 + (size_t)Nn * 16;            // Nn
  float* sdst2  = ssrc2 + Nn;                       // Nn
  float* out2   = (float*)d_out;                    // Nn*16

  dim3 blk(256);

  // ---- CSR build ----
  k_ones<<<dim3((Nn + 255) / 256), blk, 0, stream>>>(cnt, Nn);
  k_hist<<<dim3((E + 255) / 256), blk, 0, stream>>>(ei, cnt, E);
  k_scan1<<<dim3(nb), blk, 0, stream>>>(cnt, pre, part, Nn);
  k_scan2<<<dim3(1), blk, 0, stream>>>(part, nb, rowptr, Nn);
  k_scan3<<<dim3((Nn + 255) / 256), blk, 0, stream>>>(pre, part, rowptr, cursor, Nn);
  k_fillcsr<<<dim3((Etot + 255) / 256), blk, 0, stream>>>(ei, cursor, col, E, Etot);

  // ---- layer 1 ----
  const int wthr = 64 * nck * 16;
  k_wcvt<<<dim3((wthr + 255) / 256), blk, 0, stream>>>(W1, Wb, F, wthr);
  k_gemm1m<<<dim3((Nn + 127) / 128), blk, 0, stream>>>(x, Wb, xw1, Nn, F, nck);
  k_prep1<<<dim3((Nn * 8 + 255) / 256), blk, 0, stream>>>(
      xw1, a_src1, a_dst1, ssrc1, sdst1, Nn);
  k_agg1<<<dim3((Nn * 64 + 255) / 256), blk, 0, stream>>>(
      rowptr, col, ssrc1, sdst1, xw1, b1, h1, Nn);

  // ---- layer 2 ----
  k_gemm2<<<dim3((Nn * 16 + 255) / 256), blk, 0, stream>>>(h1, W2, xw2, Nn);
  k_prep2<<<dim3((Nn + 255) / 256), blk, 0, stream>>>(
      xw2, a_src2, a_dst2, ssrc2, sdst2, Nn);
  k_agg2<<<dim3((Nn * 64 + 255) / 256), blk, 0, stream>>>(
      rowptr, col, ssrc2, sdst2, xw2, b2, out2, Nn);
}

// Round 5
// 524.640 us; speedup vs baseline: 9.5851x; 1.1979x over previous
//
#include <hip/hip_runtime.h>
#include <math.h>

#define NEGS 0.2f
#define SCAN_CHUNK 2048   // 256 threads x 8 elements

typedef __attribute__((ext_vector_type(8))) short bf16x8;
typedef __attribute__((ext_vector_type(4))) float f32x4;

__device__ __forceinline__ unsigned short f2bf(float f) {
  unsigned u = __float_as_uint(f);
  u += 0x7fffu + ((u >> 16) & 1);   // RNE
  return (unsigned short)(u >> 16);
}

// ---------------- W1 -> bf16, transposed [col][k], K padded, XOR-swizzled ---
__global__ void k_wcvt(const float* __restrict__ W1, unsigned short* __restrict__ Wb,
                       int K, int nthr) {
  int t = blockIdx.x * blockDim.x + threadIdx.x;
  if (t >= nthr) return;
  int c = t & 63;
  int g = t >> 6;            // k-group of 4
  int kgl0 = g * 4;
  int ck = kgl0 >> 6;
  int kk0 = kgl0 & 63;
  unsigned short h[4];
#pragma unroll
  for (int j = 0; j < 4; ++j) {
    int kg = kgl0 + j;
    float f = (kg < K) ? W1[(size_t)kg * 64 + c] : 0.f;
    h[j] = f2bf(f);
  }
  size_t byte = (size_t)ck * 8192 + (unsigned)((c * 128 + kk0 * 2) ^ ((c & 7) << 4));
  ushort4 v = make_ushort4(h[0], h[1], h[2], h[3]);
  *(ushort4*)((char*)Wb + byte) = v;
}

// ---------------- GEMM1 (MFMA bf16): C[M,64] = A[M,K] @ W1[K,64] ------------
__global__ __launch_bounds__(256) void k_gemm1m(const float* __restrict__ A,
                                                const unsigned short* __restrict__ Wb,
                                                float* __restrict__ C,
                                                int M, int K, int nck) {
  __shared__ __align__(16) char smem[16384 + 8192];
  char* Al = smem;           // 128 rows x 128 B (bf16, swizzled)
  char* Bl = smem + 16384;   // 64 cols x 128 B (bf16, swizzled; one chunk)
  const int tid = threadIdx.x;
  const int lane = tid & 63;
  const int wid = tid >> 6;
  const int wr = wid >> 1, wc = wid & 1;
  const int bm = blockIdx.x * 128;
  const int srow = tid >> 2;     // 0..63 (pass adds 64)
  const int sq = tid & 3;        // 16-k quarter

  f32x4 acc[4][2] = {};

  for (int ck = 0; ck < nck; ++ck) {
    {
      const uint4* gs = (const uint4*)((const char*)Wb + (size_t)ck * 8192);
      uint4* ld = (uint4*)Bl;
      ld[tid * 2]     = gs[tid * 2];
      ld[tid * 2 + 1] = gs[tid * 2 + 1];
    }
#pragma unroll
    for (int p = 0; p < 2; ++p) {
      int r = srow + p * 64;
      int grow = bm + r;
      int kbase = ck * 64 + sq * 16;
      float f[16];
      if (grow < M && kbase + 16 <= K) {
        const float4* g = (const float4*)(A + (size_t)grow * K + kbase);
        float4 v0 = g[0], v1 = g[1], v2 = g[2], v3 = g[3];
        f[0]=v0.x; f[1]=v0.y; f[2]=v0.z; f[3]=v0.w;
        f[4]=v1.x; f[5]=v1.y; f[6]=v1.z; f[7]=v1.w;
        f[8]=v2.x; f[9]=v2.y; f[10]=v2.z; f[11]=v2.w;
        f[12]=v3.x; f[13]=v3.y; f[14]=v3.z; f[15]=v3.w;
      } else {
#pragma unroll
        for (int j = 0; j < 16; ++j) {
          int kg = kbase + j;
          f[j] = (grow < M && kg < K) ? A[(size_t)grow * K + kg] : 0.f;
        }
      }
      unsigned pk[8];
#pragma unroll
      for (int j = 0; j < 8; ++j)
        pk[j] = (unsigned)f2bf(f[2 * j]) | ((unsigned)f2bf(f[2 * j + 1]) << 16);
      unsigned xr = (unsigned)((r & 7) << 4);
      uint4 lo = make_uint4(pk[0], pk[1], pk[2], pk[3]);
      uint4 hi = make_uint4(pk[4], pk[5], pk[6], pk[7]);
      *(uint4*)(Al + r * 128 + ((sq * 32) ^ xr))      = lo;
      *(uint4*)(Al + r * 128 + ((sq * 32 + 16) ^ xr)) = hi;
    }
    __syncthreads();
    const int kgrp = lane >> 4;
    const int r15 = lane & 15;
#pragma unroll
    for (int ks = 0; ks < 2; ++ks) {
      bf16x8 a[4], b[2];
#pragma unroll
      for (int mr = 0; mr < 4; ++mr) {
        int row = wr * 64 + mr * 16 + r15;
        a[mr] = *(const bf16x8*)(Al + row * 128 +
                 ((ks * 64 + kgrp * 16) ^ ((row & 7) << 4)));
      }
#pragma unroll
      for (int nc = 0; nc < 2; ++nc) {
        int col = wc * 32 + nc * 16 + r15;
        b[nc] = *(const bf16x8*)(Bl + col * 128 +
                 ((ks * 64 + kgrp * 16) ^ ((col & 7) << 4)));
      }
#pragma unroll
      for (int mr = 0; mr < 4; ++mr)
#pragma unroll
        for (int nc = 0; nc < 2; ++nc)
          acc[mr][nc] = __builtin_amdgcn_mfma_f32_16x16x32_bf16(
              a[mr], b[nc], acc[mr][nc], 0, 0, 0);
    }
    __syncthreads();
  }
  const int r15 = lane & 15;
  const int rg4 = (lane >> 4) * 4;
#pragma unroll
  for (int mr = 0; mr < 4; ++mr) {
#pragma unroll
    for (int nc = 0; nc < 2; ++nc) {
      int row0 = bm + wr * 64 + mr * 16 + rg4;
      int colg = wc * 32 + nc * 16 + r15;
#pragma unroll
      for (int j = 0; j < 4; ++j) {
        int grow = row0 + j;
        if (grow < M) C[(size_t)grow * 64 + colg] = acc[mr][nc][j];
      }
    }
  }
}

// ---------------- CSR build: histogram -> scan -> scatter -------------------
__global__ void k_ones(int* __restrict__ cnt, int Nn) {
  int i = blockIdx.x * blockDim.x + threadIdx.x;
  if (i < Nn) cnt[i] = 1;   // self-loop
}

__global__ void k_hist(const int* __restrict__ ei, int* __restrict__ cnt, int E) {
  int e = blockIdx.x * blockDim.x + threadIdx.x;
  if (e < E) atomicAdd(&cnt[ei[E + e]], 1);
}

__global__ __launch_bounds__(256) void k_scan1(const int* __restrict__ cnt,
                                               int* __restrict__ pre,
                                               int* __restrict__ part, int Nn) {
  __shared__ int sh[256];
  const int t = threadIdx.x;
  const int base = blockIdx.x * SCAN_CHUNK + t * 8;
  int e[8];
  int ts = 0;
#pragma unroll
  for (int j = 0; j < 8; ++j) {
    int idx = base + j;
    e[j] = (idx < Nn) ? cnt[idx] : 0;
    ts += e[j];
  }
  sh[t] = ts;
  __syncthreads();
  for (int off = 1; off < 256; off <<= 1) {
    int v = (t >= off) ? sh[t - off] : 0;
    __syncthreads();
    sh[t] += v;
    __syncthreads();
  }
  int excl = sh[t] - ts;
  int w = 0;
#pragma unroll
  for (int j = 0; j < 8; ++j) {
    int idx = base + j;
    if (idx < Nn) pre[idx] = excl + w;
    w += e[j];
  }
  if (t == 255) part[blockIdx.x] = sh[255];
}

__global__ void k_scan2(int* __restrict__ part, int nb,
                        int* __restrict__ rowptr, int Nn) {
  if (blockIdx.x == 0 && threadIdx.x == 0) {
    int run = 0;
    for (int b = 0; b < nb; ++b) {
      int v = part[b];
      part[b] = run;
      run += v;
    }
    rowptr[Nn] = run;
  }
}

__global__ void k_scan3(const int* __restrict__ pre, const int* __restrict__ part,
                        int* __restrict__ rowptr, int* __restrict__ cursor, int Nn) {
  int i = blockIdx.x * blockDim.x + threadIdx.x;
  if (i >= Nn) return;
  int v = pre[i] + part[i / SCAN_CHUNK];
  rowptr[i] = v;
  cursor[i] = v;
}

__global__ void k_fillcsr(const int* __restrict__ ei, int* __restrict__ cursor,
                          int* __restrict__ col, int E, int Etot) {
  int e = blockIdx.x * blockDim.x + threadIdx.x;
  if (e >= Etot) return;
  int s, d;
  if (e < E) { s = ei[e]; d = ei[E + e]; }
  else       { s = d = e - E; }
  int pos = atomicAdd(&cursor[d], 1);
  col[pos] = s;
}

// ---------------- layer-1 prep: attention halves ----------------------------
__global__ void k_prep1(const float* __restrict__ xw,
                        const float* __restrict__ asr,
                        const float* __restrict__ adt,
                        float* __restrict__ ssrc, float* __restrict__ sdst,
                        int Nn) {
  int idx = blockIdx.x * blockDim.x + threadIdx.x;
  if (idx >= Nn * 8) return;
  int h = idx & 7;
  const float* xr = xw + (size_t)(idx >> 3) * 64 + h * 8;
  float ss = 0.f, sd = 0.f;
#pragma unroll
  for (int c = 0; c < 8; ++c) {
    float v = xr[c];
    ss += v * asr[h * 8 + c];
    sd += v * adt[h * 8 + c];
  }
  ssrc[idx] = ss;
  sdst[idx] = sd;
}

// ---------------- layer-1 aggregate: single pass (no max), one wave/node ----
__global__ __launch_bounds__(256) void k_agg1(const int* __restrict__ rowptr,
                                              const int* __restrict__ col,
                                              const float* __restrict__ ssrc,
                                              const float* __restrict__ sdst,
                                              const float* __restrict__ xw,
                                              const float* __restrict__ b1,
                                              float* __restrict__ h1, int Nn) {
  int wid = (blockIdx.x * 256 + threadIdx.x) >> 6;
  if (wid >= Nn) return;
  int lane = threadIdx.x & 63;
  int h = lane >> 3;
  float sd = sdst[wid * 8 + h];
  int start = rowptr[wid], end = rowptr[wid + 1];
  float den = 0.f, acc = 0.f;
  for (int i = start; i < end; ++i) {
    int s = col[i];
    float v = ssrc[s * 8 + h] + sd;
    v = v > 0.f ? v : NEGS * v;
    float p = __expf(v);   // logits |v| ~ O(1): no max shift needed in f32
    den += p;
    acc = fmaf(p, xw[(size_t)s * 64 + lane], acc);
  }
  float o = acc / den + b1[lane];
  h1[(size_t)wid * 64 + lane] = o > 0.f ? o : (__expf(o) - 1.f);
}

// ---------------- GEMM2 + prep2 fused: xw2 = h1 @ W2; ssrc2/sdst2 dots ------
__global__ __launch_bounds__(256) void k_gemm2p(const float* __restrict__ h1,
                                                const float* __restrict__ W2,
                                                const float* __restrict__ asr,
                                                const float* __restrict__ adt,
                                                float* __restrict__ xw2,
                                                float* __restrict__ ssrc,
                                                float* __restrict__ sdst, int Nn) {
  __shared__ float w[64 * 16];
  int tid = threadIdx.x;
  for (int i = tid; i < 1024; i += 256) w[i] = W2[i];
  __syncthreads();
  int idx = blockIdx.x * 256 + tid;
  if (idx >= Nn * 16) return;
  int n = idx >> 4, c = idx & 15;
  const float* hr = h1 + (size_t)n * 64;
  float acc = 0.f;
#pragma unroll 8
  for (int k = 0; k < 64; ++k) acc += hr[k] * w[k * 16 + c];
  xw2[idx] = acc;
  float ssv = acc * asr[c], sdv = acc * adt[c];
#pragma unroll
  for (int off = 1; off < 16; off <<= 1) {
    ssv += __shfl_xor(ssv, off);
    sdv += __shfl_xor(sdv, off);
  }
  if (c == 0) { ssrc[n] = ssv; sdst[n] = sdv; }
}

// ---------------- layer-2 aggregate: single pass + fused log_softmax --------
__global__ __launch_bounds__(256) void k_agg2(const int* __restrict__ rowptr,
                                              const int* __restrict__ col,
                                              const float* __restrict__ ssrc,
                                              const float* __restrict__ sdst,
                                              const float* __restrict__ xw2,
                                              const float* __restrict__ b2,
                                              float* __restrict__ out, int Nn) {
  int wid = (blockIdx.x * 256 + threadIdx.x) >> 6;
  if (wid >= Nn) return;
  int lane = threadIdx.x & 63;
  int slot = lane >> 4, c = lane & 15;
  float sd = sdst[wid];
  int start = rowptr[wid], end = rowptr[wid + 1];
  float den = 0.f, acc = 0.f;
  for (int i = start + slot; i < end; i += 4) {
    int s = col[i];
    float v = ssrc[s] + sd;
    v = v > 0.f ? v : NEGS * v;
    float p = __expf(v);
    den += p;
    acc = fmaf(p, xw2[(size_t)s * 16 + c], acc);
  }
  den += __shfl_xor(den, 16);
  den += __shfl_xor(den, 32);
  acc += __shfl_xor(acc, 16);
  acc += __shfl_xor(acc, 32);
  float o = acc / den + b2[c];
  float mx = o;
#pragma unroll
  for (int off = 1; off < 16; off <<= 1) mx = fmaxf(mx, __shfl_xor(mx, off));
  float ex = __expf(o - mx);
  float ssum = ex;
#pragma unroll
  for (int off = 1; off < 16; off <<= 1) ssum += __shfl_xor(ssum, off);
  float r = o - mx - __logf(ssum);
  if (slot == 0) out[(size_t)wid * 16 + c] = r;
}

extern "C" void kernel_launch(void* const* d_in, const int* in_sizes, int n_in,
                              void* d_out, int out_size, void* d_ws, size_t ws_size,
                              hipStream_t stream) {
  const float* x      = (const float*)d_in[0];
  const int* ei       = (const int*)d_in[1];
  const float* W1     = (const float*)d_in[2];
  const float* a_src1 = (const float*)d_in[3];
  const float* a_dst1 = (const float*)d_in[4];
  const float* b1     = (const float*)d_in[5];
  const float* W2     = (const float*)d_in[6];
  const float* a_src2 = (const float*)d_in[7];
  const float* a_dst2 = (const float*)d_in[8];
  const float* b2     = (const float*)d_in[9];

  const int F    = in_sizes[2] / 64;   // 500
  const int Nn   = in_sizes[0] / F;    // 100000
  const int E    = in_sizes[1] / 2;    // 1600000
  const int Etot = E + Nn;
  const int nb   = (Nn + SCAN_CHUNK - 1) / SCAN_CHUNK;
  const int nck  = (F + 63) >> 6;      // K chunks of 64

  // ---- workspace layout (4-byte units) ----
  float* ws = (float*)d_ws;
  float* xw1    = ws;                               // Nn*64
  float* h1     = xw1 + (size_t)Nn * 64;            // Nn*64
  float* ssrc1  = h1 + (size_t)Nn * 64;             // Nn*8
  float* sdst1  = ssrc1 + (size_t)Nn * 8;           // Nn*8
  int* cnt      = (int*)(sdst1 + (size_t)Nn * 8);   // Nn
  int* pre      = cnt + Nn;                         // Nn
  int* rowptr   = pre + Nn;                         // Nn+1
  int* cursor   = rowptr + Nn + 1;                  // Nn
  int* part     = cursor + Nn;                      // nb (+pad to 256)
  int* col      = part + 256;                       // Etot
  unsigned short* Wb = (unsigned short*)(col + ((Etot + 7) & ~7));  // nck*4096 shorts
  // layer-2 buffers reuse xw1 region (dead after k_agg1)
  float* xw2    = xw1;                              // Nn*16
  float* ssrc2  = xw2 + (size_t)Nn * 16;            // Nn
  float* sdst2  = ssrc2 + Nn;                       // Nn
  float* out2   = (float*)d_out;                    // Nn*16

  dim3 blk(256);

  // ---- CSR build ----
  k_ones<<<dim3((Nn + 255) / 256), blk, 0, stream>>>(cnt, Nn);
  k_hist<<<dim3((E + 255) / 256), blk, 0, stream>>>(ei, cnt, E);
  k_scan1<<<dim3(nb), blk, 0, stream>>>(cnt, pre, part, Nn);
  k_scan2<<<dim3(1), blk, 0, stream>>>(part, nb, rowptr, Nn);
  k_scan3<<<dim3((Nn + 255) / 256), blk, 0, stream>>>(pre, part, rowptr, cursor, Nn);
  k_fillcsr<<<dim3((Etot + 255) / 256), blk, 0, stream>>>(ei, cursor, col, E, Etot);

  // ---- layer 1 ----
  const int wthr = 64 * nck * 16;
  k_wcvt<<<dim3((wthr + 255) / 256), blk, 0, stream>>>(W1, Wb, F, wthr);
  k_gemm1m<<<dim3((Nn + 127) / 128), blk, 0, stream>>>(x, Wb, xw1, Nn, F, nck);
  k_prep1<<<dim3((Nn * 8 + 255) / 256), blk, 0, stream>>>(
      xw1, a_src1, a_dst1, ssrc1, sdst1, Nn);
  k_agg1<<<dim3((Nn * 64 + 255) / 256), blk, 0, stream>>>(
      rowptr, col, ssrc1, sdst1, xw1, b1, h1, Nn);

  // ---- layer 2 ----
  k_gemm2p<<<dim3((Nn * 16 + 255) / 256), blk, 0, stream>>>(
      h1, W2, a_src2, a_dst2, xw2, ssrc2, sdst2, Nn);
  k_agg2<<<dim3((Nn * 64 + 255) / 256), blk, 0, stream>>>(
      rowptr, col, ssrc2, sdst2, xw2, b2, out2, Nn);
}

// Round 6
// 421.689 us; speedup vs baseline: 11.9252x; 1.2441x over previous
//
#include <hip/hip_runtime.h>
#include <math.h>

#define NEGS 0.2f
#define SCAN_CHUNK 2048   // 256 threads x 8 elements

typedef __attribute__((ext_vector_type(8))) short bf16x8;
typedef __attribute__((ext_vector_type(4))) float f32x4;

__device__ __forceinline__ unsigned short f2bf(float f) {
  unsigned u = __float_as_uint(f);
  u += 0x7fffu + ((u >> 16) & 1);   // RNE
  return (unsigned short)(u >> 16);
}
__device__ __forceinline__ float bf2f(unsigned short u) {
  return __uint_as_float((unsigned)u << 16);
}

// ---------------- W1 -> bf16, transposed [col][k], K padded, XOR-swizzled ---
__global__ void k_wcvt(const float* __restrict__ W1, unsigned short* __restrict__ Wb,
                       int K, int nthr) {
  int t = blockIdx.x * blockDim.x + threadIdx.x;
  if (t >= nthr) return;
  int c = t & 63;
  int g = t >> 6;            // k-group of 4
  int kgl0 = g * 4;
  int ck = kgl0 >> 6;
  int kk0 = kgl0 & 63;
  unsigned short h[4];
#pragma unroll
  for (int j = 0; j < 4; ++j) {
    int kg = kgl0 + j;
    float f = (kg < K) ? W1[(size_t)kg * 64 + c] : 0.f;
    h[j] = f2bf(f);
  }
  size_t byte = (size_t)ck * 8192 + (unsigned)((c * 128 + kk0 * 2) ^ ((c & 7) << 4));
  ushort4 v = make_ushort4(h[0], h[1], h[2], h[3]);
  *(ushort4*)((char*)Wb + byte) = v;
}

// ---------------- GEMM1 (MFMA bf16): xwb[M,64](bf16) = A[M,K] @ W1[K,64] ----
__global__ __launch_bounds__(256) void k_gemm1m(const float* __restrict__ A,
                                                const unsigned short* __restrict__ Wb,
                                                unsigned short* __restrict__ C,
                                                int M, int K, int nck) {
  __shared__ __align__(16) char smem[16384 + 8192];
  char* Al = smem;           // 128 rows x 128 B (bf16, swizzled)
  char* Bl = smem + 16384;   // 64 cols x 128 B (bf16, swizzled; one chunk)
  const int tid = threadIdx.x;
  const int lane = tid & 63;
  const int wid = tid >> 6;
  const int wr = wid >> 1, wc = wid & 1;
  const int bm = blockIdx.x * 128;
  const int srow = tid >> 2;     // 0..63 (pass adds 64)
  const int sq = tid & 3;        // 16-k quarter

  f32x4 acc[4][2] = {};

  for (int ck = 0; ck < nck; ++ck) {
    {
      const uint4* gs = (const uint4*)((const char*)Wb + (size_t)ck * 8192);
      uint4* ld = (uint4*)Bl;
      ld[tid * 2]     = gs[tid * 2];
      ld[tid * 2 + 1] = gs[tid * 2 + 1];
    }
#pragma unroll
    for (int p = 0; p < 2; ++p) {
      int r = srow + p * 64;
      int grow = bm + r;
      int kbase = ck * 64 + sq * 16;
      float f[16];
      if (grow < M && kbase + 16 <= K) {
        const float4* g = (const float4*)(A + (size_t)grow * K + kbase);
        float4 v0 = g[0], v1 = g[1], v2 = g[2], v3 = g[3];
        f[0]=v0.x; f[1]=v0.y; f[2]=v0.z; f[3]=v0.w;
        f[4]=v1.x; f[5]=v1.y; f[6]=v1.z; f[7]=v1.w;
        f[8]=v2.x; f[9]=v2.y; f[10]=v2.z; f[11]=v2.w;
        f[12]=v3.x; f[13]=v3.y; f[14]=v3.z; f[15]=v3.w;
      } else {
#pragma unroll
        for (int j = 0; j < 16; ++j) {
          int kg = kbase + j;
          f[j] = (grow < M && kg < K) ? A[(size_t)grow * K + kg] : 0.f;
        }
      }
      unsigned pk[8];
#pragma unroll
      for (int j = 0; j < 8; ++j)
        pk[j] = (unsigned)f2bf(f[2 * j]) | ((unsigned)f2bf(f[2 * j + 1]) << 16);
      unsigned xr = (unsigned)((r & 7) << 4);
      uint4 lo = make_uint4(pk[0], pk[1], pk[2], pk[3]);
      uint4 hi = make_uint4(pk[4], pk[5], pk[6], pk[7]);
      *(uint4*)(Al + r * 128 + ((sq * 32) ^ xr))      = lo;
      *(uint4*)(Al + r * 128 + ((sq * 32 + 16) ^ xr)) = hi;
    }
    __syncthreads();
    const int kgrp = lane >> 4;
    const int r15 = lane & 15;
#pragma unroll
    for (int ks = 0; ks < 2; ++ks) {
      bf16x8 a[4], b[2];
#pragma unroll
      for (int mr = 0; mr < 4; ++mr) {
        int row = wr * 64 + mr * 16 + r15;
        a[mr] = *(const bf16x8*)(Al + row * 128 +
                 ((ks * 64 + kgrp * 16) ^ ((row & 7) << 4)));
      }
#pragma unroll
      for (int nc = 0; nc < 2; ++nc) {
        int col = wc * 32 + nc * 16 + r15;
        b[nc] = *(const bf16x8*)(Bl + col * 128 +
                 ((ks * 64 + kgrp * 16) ^ ((col & 7) << 4)));
      }
#pragma unroll
      for (int mr = 0; mr < 4; ++mr)
#pragma unroll
        for (int nc = 0; nc < 2; ++nc)
          acc[mr][nc] = __builtin_amdgcn_mfma_f32_16x16x32_bf16(
              a[mr], b[nc], acc[mr][nc], 0, 0, 0);
    }
    __syncthreads();
  }
  const int r15 = lane & 15;
  const int rg4 = (lane >> 4) * 4;
#pragma unroll
  for (int mr = 0; mr < 4; ++mr) {
#pragma unroll
    for (int nc = 0; nc < 2; ++nc) {
      int row0 = bm + wr * 64 + mr * 16 + rg4;
      int colg = wc * 32 + nc * 16 + r15;
#pragma unroll
      for (int j = 0; j < 4; ++j) {
        int grow = row0 + j;
        if (grow < M) C[(size_t)grow * 64 + colg] = f2bf(acc[mr][nc][j]);
      }
    }
  }
}

// ---------------- CSR build: histogram -> scan -> scatter -------------------
__global__ void k_ones(int* __restrict__ cnt, int Nn) {
  int i = blockIdx.x * blockDim.x + threadIdx.x;
  if (i < Nn) cnt[i] = 1;   // self-loop
}

__global__ void k_hist(const int* __restrict__ ei, int* __restrict__ cnt, int E) {
  int e = blockIdx.x * blockDim.x + threadIdx.x;
  if (e < E) atomicAdd(&cnt[ei[E + e]], 1);
}

__global__ __launch_bounds__(256) void k_scan1(const int* __restrict__ cnt,
                                               int* __restrict__ pre,
                                               int* __restrict__ part, int Nn) {
  __shared__ int sh[256];
  const int t = threadIdx.x;
  const int base = blockIdx.x * SCAN_CHUNK + t * 8;
  int e[8];
  int ts = 0;
#pragma unroll
  for (int j = 0; j < 8; ++j) {
    int idx = base + j;
    e[j] = (idx < Nn) ? cnt[idx] : 0;
    ts += e[j];
  }
  sh[t] = ts;
  __syncthreads();
  for (int off = 1; off < 256; off <<= 1) {
    int v = (t >= off) ? sh[t - off] : 0;
    __syncthreads();
    sh[t] += v;
    __syncthreads();
  }
  int excl = sh[t] - ts;
  int w = 0;
#pragma unroll
  for (int j = 0; j < 8; ++j) {
    int idx = base + j;
    if (idx < Nn) pre[idx] = excl + w;
    w += e[j];
  }
  if (t == 255) part[blockIdx.x] = sh[255];
}

__global__ void k_scan2(int* __restrict__ part, int nb,
                        int* __restrict__ rowptr, int Nn) {
  if (blockIdx.x == 0 && threadIdx.x == 0) {
    int run = 0;
    for (int b = 0; b < nb; ++b) {
      int v = part[b];
      part[b] = run;
      run += v;
    }
    rowptr[Nn] = run;
  }
}

__global__ void k_scan3(const int* __restrict__ pre, const int* __restrict__ part,
                        int* __restrict__ rowptr, int* __restrict__ cursor, int Nn) {
  int i = blockIdx.x * blockDim.x + threadIdx.x;
  if (i >= Nn) return;
  int v = pre[i] + part[i / SCAN_CHUNK];
  rowptr[i] = v;
  cursor[i] = v;
}

__global__ void k_fillcsr(const int* __restrict__ ei, int* __restrict__ cursor,
                          int* __restrict__ col, int E, int Etot) {
  int e = blockIdx.x * blockDim.x + threadIdx.x;
  if (e >= Etot) return;
  int s, d;
  if (e < E) { s = ei[e]; d = ei[E + e]; }
  else       { s = d = e - E; }
  int pos = atomicAdd(&cursor[d], 1);
  col[pos] = s;
}

// ---------------- layer-1 prep: attention halves (bf16 input) ---------------
__global__ void k_prep1(const unsigned short* __restrict__ xwb,
                        const float* __restrict__ asr,
                        const float* __restrict__ adt,
                        float* __restrict__ ssrc, float* __restrict__ sdst,
                        int Nn) {
  int idx = blockIdx.x * blockDim.x + threadIdx.x;
  if (idx >= Nn * 8) return;
  int h = idx & 7;
  const uint4 v = *(const uint4*)(xwb + (size_t)(idx >> 3) * 64 + h * 8);
  float f[8];
  f[0] = __uint_as_float(v.x << 16); f[1] = __uint_as_float(v.x & 0xffff0000u);
  f[2] = __uint_as_float(v.y << 16); f[3] = __uint_as_float(v.y & 0xffff0000u);
  f[4] = __uint_as_float(v.z << 16); f[5] = __uint_as_float(v.z & 0xffff0000u);
  f[6] = __uint_as_float(v.w << 16); f[7] = __uint_as_float(v.w & 0xffff0000u);
  float ss = 0.f, sd = 0.f;
#pragma unroll
  for (int c = 0; c < 8; ++c) {
    ss += f[c] * asr[h * 8 + c];
    sd += f[c] * adt[h * 8 + c];
  }
  ssrc[idx] = ss;
  sdst[idx] = sd;
}

// ---------------- layer-1 aggregate: 4x unrolled gather, one wave/node ------
__global__ __launch_bounds__(256) void k_agg1(const int* __restrict__ rowptr,
                                              const int* __restrict__ col,
                                              const float* __restrict__ ssrc,
                                              const float* __restrict__ sdst,
                                              const unsigned short* __restrict__ xwb,
                                              const float* __restrict__ b1,
                                              float* __restrict__ h1, int Nn) {
  int wid = (blockIdx.x * 256 + threadIdx.x) >> 6;
  if (wid >= Nn) return;
  int lane = threadIdx.x & 63;
  int h = lane >> 3;
  float sd = sdst[wid * 8 + h];
  int start = rowptr[wid], end = rowptr[wid + 1];
  float den = 0.f, acc = 0.f;
  int i = start;
  for (; i + 4 <= end; i += 4) {
    int s0 = col[i], s1 = col[i + 1], s2 = col[i + 2], s3 = col[i + 3];
    // issue all 8 gathers before any math
    float w0 = bf2f(xwb[(size_t)s0 * 64 + lane]);
    float w1 = bf2f(xwb[(size_t)s1 * 64 + lane]);
    float w2 = bf2f(xwb[(size_t)s2 * 64 + lane]);
    float w3 = bf2f(xwb[(size_t)s3 * 64 + lane]);
    float e0 = ssrc[s0 * 8 + h], e1 = ssrc[s1 * 8 + h];
    float e2 = ssrc[s2 * 8 + h], e3 = ssrc[s3 * 8 + h];
    float v0 = e0 + sd; v0 = v0 > 0.f ? v0 : NEGS * v0;
    float v1 = e1 + sd; v1 = v1 > 0.f ? v1 : NEGS * v1;
    float v2 = e2 + sd; v2 = v2 > 0.f ? v2 : NEGS * v2;
    float v3 = e3 + sd; v3 = v3 > 0.f ? v3 : NEGS * v3;
    float p0 = __expf(v0), p1 = __expf(v1), p2 = __expf(v2), p3 = __expf(v3);
    den += (p0 + p1) + (p2 + p3);
    acc = fmaf(p0, w0, acc);
    acc = fmaf(p1, w1, acc);
    acc = fmaf(p2, w2, acc);
    acc = fmaf(p3, w3, acc);
  }
  for (; i < end; ++i) {
    int s = col[i];
    float w = bf2f(xwb[(size_t)s * 64 + lane]);
    float v = ssrc[s * 8 + h] + sd;
    v = v > 0.f ? v : NEGS * v;
    float p = __expf(v);
    den += p;
    acc = fmaf(p, w, acc);
  }
  float o = acc / den + b1[lane];
  h1[(size_t)wid * 64 + lane] = o > 0.f ? o : (__expf(o) - 1.f);
}

// ---------------- GEMM2 + prep2 fused: xw2 = h1 @ W2; ssrc2/sdst2 dots ------
__global__ __launch_bounds__(256) void k_gemm2p(const float* __restrict__ h1,
                                                const float* __restrict__ W2,
                                                const float* __restrict__ asr,
                                                const float* __restrict__ adt,
                                                float* __restrict__ xw2,
                                                float* __restrict__ ssrc,
                                                float* __restrict__ sdst, int Nn) {
  __shared__ float w[64 * 16];
  int tid = threadIdx.x;
  for (int i = tid; i < 1024; i += 256) w[i] = W2[i];
  __syncthreads();
  int idx = blockIdx.x * 256 + tid;
  if (idx >= Nn * 16) return;
  int n = idx >> 4, c = idx & 15;
  const float* hr = h1 + (size_t)n * 64;
  float acc = 0.f;
#pragma unroll 8
  for (int k = 0; k < 64; ++k) acc += hr[k] * w[k * 16 + c];
  xw2[idx] = acc;
  float ssv = acc * asr[c], sdv = acc * adt[c];
#pragma unroll
  for (int off = 1; off < 16; off <<= 1) {
    ssv += __shfl_xor(ssv, off);
    sdv += __shfl_xor(sdv, off);
  }
  if (c == 0) { ssrc[n] = ssv; sdst[n] = sdv; }
}

// ---------------- layer-2 aggregate: 2x unrolled + fused log_softmax --------
__global__ __launch_bounds__(256) void k_agg2(const int* __restrict__ rowptr,
                                              const int* __restrict__ col,
                                              const float* __restrict__ ssrc,
                                              const float* __restrict__ sdst,
                                              const float* __restrict__ xw2,
                                              const float* __restrict__ b2,
                                              float* __restrict__ out, int Nn) {
  int wid = (blockIdx.x * 256 + threadIdx.x) >> 6;
  if (wid >= Nn) return;
  int lane = threadIdx.x & 63;
  int slot = lane >> 4, c = lane & 15;
  float sd = sdst[wid];
  int start = rowptr[wid], end = rowptr[wid + 1];
  float den = 0.f, acc = 0.f;
  int i = start + slot;
  for (; i + 4 < end; i += 8) {
    int s0 = col[i], s1 = col[i + 4];
    float w0 = xw2[(size_t)s0 * 16 + c];
    float w1 = xw2[(size_t)s1 * 16 + c];
    float v0 = ssrc[s0] + sd; v0 = v0 > 0.f ? v0 : NEGS * v0;
    float v1 = ssrc[s1] + sd; v1 = v1 > 0.f ? v1 : NEGS * v1;
    float p0 = __expf(v0), p1 = __expf(v1);
    den += p0 + p1;
    acc = fmaf(p0, w0, acc);
    acc = fmaf(p1, w1, acc);
  }
  if (i < end) {
    int s = col[i];
    float v = ssrc[s] + sd;
    v = v > 0.f ? v : NEGS * v;
    float p = __expf(v);
    den += p;
    acc = fmaf(p, xw2[(size_t)s * 16 + c], acc);
  }
  den += __shfl_xor(den, 16);
  den += __shfl_xor(den, 32);
  acc += __shfl_xor(acc, 16);
  acc += __shfl_xor(acc, 32);
  float o = acc / den + b2[c];
  float mx = o;
#pragma unroll
  for (int off = 1; off < 16; off <<= 1) mx = fmaxf(mx, __shfl_xor(mx, off));
  float ex = __expf(o - mx);
  float ssum = ex;
#pragma unroll
  for (int off = 1; off < 16; off <<= 1) ssum += __shfl_xor(ssum, off);
  float r = o - mx - __logf(ssum);
  if (slot == 0) out[(size_t)wid * 16 + c] = r;
}

extern "C" void kernel_launch(void* const* d_in, const int* in_sizes, int n_in,
                              void* d_out, int out_size, void* d_ws, size_t ws_size,
                              hipStream_t stream) {
  const float* x      = (const float*)d_in[0];
  const int* ei       = (const int*)d_in[1];
  const float* W1     = (const float*)d_in[2];
  const float* a_src1 = (const float*)d_in[3];
  const float* a_dst1 = (const float*)d_in[4];
  const float* b1     = (const float*)d_in[5];
  const float* W2     = (const float*)d_in[6];
  const float* a_src2 = (const float*)d_in[7];
  const float* a_dst2 = (const float*)d_in[8];
  const float* b2     = (const float*)d_in[9];

  const int F    = in_sizes[2] / 64;   // 500
  const int Nn   = in_sizes[0] / F;    // 100000
  const int E    = in_sizes[1] / 2;    // 1600000
  const int Etot = E + Nn;
  const int nb   = (Nn + SCAN_CHUNK - 1) / SCAN_CHUNK;
  const int nck  = (F + 63) >> 6;      // K chunks of 64

  // ---- workspace layout (4-byte units) ----
  float* ws = (float*)d_ws;
  unsigned short* xwb = (unsigned short*)ws;        // Nn*64 bf16 = Nn*32 f32-units
  float* h1     = ws + (size_t)Nn * 32;             // Nn*64
  float* ssrc1  = h1 + (size_t)Nn * 64;             // Nn*8
  float* sdst1  = ssrc1 + (size_t)Nn * 8;           // Nn*8
  int* cnt      = (int*)(sdst1 + (size_t)Nn * 8);   // Nn
  int* pre      = cnt + Nn;                         // Nn
  int* rowptr   = pre + Nn;                         // Nn+1
  int* cursor   = rowptr + Nn + 1;                  // Nn
  int* part     = cursor + Nn;                      // nb (+pad to 256)
  int* col      = part + 256;                       // Etot
  unsigned short* Wb = (unsigned short*)(col + ((Etot + 7) & ~7));  // nck*4096
  // layer-2 buffers reuse xwb region (dead after k_agg1): 18Nn <= 32Nn
  float* xw2    = ws;                               // Nn*16
  float* ssrc2  = xw2 + (size_t)Nn * 16;            // Nn
  float* sdst2  = ssrc2 + Nn;                       // Nn
  float* out2   = (float*)d_out;                    // Nn*16

  dim3 blk(256);

  // ---- CSR build ----
  k_ones<<<dim3((Nn + 255) / 256), blk, 0, stream>>>(cnt, Nn);
  k_hist<<<dim3((E + 255) / 256), blk, 0, stream>>>(ei, cnt, E);
  k_scan1<<<dim3(nb), blk, 0, stream>>>(cnt, pre, part, Nn);
  k_scan2<<<dim3(1), blk, 0, stream>>>(part, nb, rowptr, Nn);
  k_scan3<<<dim3((Nn + 255) / 256), blk, 0, stream>>>(pre, part, rowptr, cursor, Nn);
  k_fillcsr<<<dim3((Etot + 255) / 256), blk, 0, stream>>>(ei, cursor, col, E, Etot);

  // ---- layer 1 ----
  const int wthr = 64 * nck * 16;
  k_wcvt<<<dim3((wthr + 255) / 256), blk, 0, stream>>>(W1, Wb, F, wthr);
  k_gemm1m<<<dim3((Nn + 127) / 128), blk, 0, stream>>>(x, Wb, xwb, Nn, F, nck);
  k_prep1<<<dim3((Nn * 8 + 255) / 256), blk, 0, stream>>>(
      xwb, a_src1, a_dst1, ssrc1, sdst1, Nn);
  k_agg1<<<dim3((Nn * 64 + 255) / 256), blk, 0, stream>>>(
      rowptr, col, ssrc1, sdst1, xwb, b1, h1, Nn);

  // ---- layer 2 ----
  k_gemm2p<<<dim3((Nn * 16 + 255) / 256), blk, 0, stream>>>(
      h1, W2, a_src2, a_dst2, xw2, ssrc2, sdst2, Nn);
  k_agg2<<<dim3((Nn * 64 + 255) / 256), blk, 0, stream>>>(
      rowptr, col, ssrc2, sdst2, xw2, b2, out2, Nn);
}

// Round 7
// 255.252 us; speedup vs baseline: 19.7010x; 1.6521x over previous
//
#include <hip/hip_runtime.h>
#include <math.h>

#define NEGS 0.2f
#define BSH 9                 // bucket shift: 512 nodes per bucket
#define TS 4096               // edges per partition tile

typedef __attribute__((ext_vector_type(8))) short bf16x8;
typedef __attribute__((ext_vector_type(4))) float f32x4;

__device__ __forceinline__ unsigned short f2bf(float f) {
  unsigned u = __float_as_uint(f);
  u += 0x7fffu + ((u >> 16) & 1);   // RNE
  return (unsigned short)(u >> 16);
}
__device__ __forceinline__ float bf2f(unsigned short u) {
  return __uint_as_float((unsigned)u << 16);
}

// ---------------- W1 -> bf16, transposed [col][k], K padded, XOR-swizzled ---
__global__ void k_wcvt(const float* __restrict__ W1, unsigned short* __restrict__ Wb,
                       int K, int nthr) {
  int t = blockIdx.x * blockDim.x + threadIdx.x;
  if (t >= nthr) return;
  int c = t & 63;
  int g = t >> 6;
  int kgl0 = g * 4;
  int ck = kgl0 >> 6;
  int kk0 = kgl0 & 63;
  unsigned short h[4];
#pragma unroll
  for (int j = 0; j < 4; ++j) {
    int kg = kgl0 + j;
    float f = (kg < K) ? W1[(size_t)kg * 64 + c] : 0.f;
    h[j] = f2bf(f);
  }
  size_t byte = (size_t)ck * 8192 + (unsigned)((c * 128 + kk0 * 2) ^ ((c & 7) << 4));
  ushort4 v = make_ushort4(h[0], h[1], h[2], h[3]);
  *(ushort4*)((char*)Wb + byte) = v;
}

// ---------------- GEMM1 (MFMA bf16): xwb[M,64](bf16) = A[M,K] @ W1[K,64] ----
__global__ __launch_bounds__(256) void k_gemm1m(const float* __restrict__ A,
                                                const unsigned short* __restrict__ Wb,
                                                unsigned short* __restrict__ C,
                                                int M, int K, int nck) {
  __shared__ __align__(16) char smem[16384 + 8192];
  char* Al = smem;
  char* Bl = smem + 16384;
  const int tid = threadIdx.x;
  const int lane = tid & 63;
  const int wid = tid >> 6;
  const int wr = wid >> 1, wc = wid & 1;
  const int bm = blockIdx.x * 128;
  const int srow = tid >> 2;
  const int sq = tid & 3;

  f32x4 acc[4][2] = {};

  for (int ck = 0; ck < nck; ++ck) {
    {
      const uint4* gs = (const uint4*)((const char*)Wb + (size_t)ck * 8192);
      uint4* ld = (uint4*)Bl;
      ld[tid * 2]     = gs[tid * 2];
      ld[tid * 2 + 1] = gs[tid * 2 + 1];
    }
#pragma unroll
    for (int p = 0; p < 2; ++p) {
      int r = srow + p * 64;
      int grow = bm + r;
      int kbase = ck * 64 + sq * 16;
      float f[16];
      if (grow < M && kbase + 16 <= K) {
        const float4* g = (const float4*)(A + (size_t)grow * K + kbase);
        float4 v0 = g[0], v1 = g[1], v2 = g[2], v3 = g[3];
        f[0]=v0.x; f[1]=v0.y; f[2]=v0.z; f[3]=v0.w;
        f[4]=v1.x; f[5]=v1.y; f[6]=v1.z; f[7]=v1.w;
        f[8]=v2.x; f[9]=v2.y; f[10]=v2.z; f[11]=v2.w;
        f[12]=v3.x; f[13]=v3.y; f[14]=v3.z; f[15]=v3.w;
      } else {
#pragma unroll
        for (int j = 0; j < 16; ++j) {
          int kg = kbase + j;
          f[j] = (grow < M && kg < K) ? A[(size_t)grow * K + kg] : 0.f;
        }
      }
      unsigned pk[8];
#pragma unroll
      for (int j = 0; j < 8; ++j)
        pk[j] = (unsigned)f2bf(f[2 * j]) | ((unsigned)f2bf(f[2 * j + 1]) << 16);
      unsigned xr = (unsigned)((r & 7) << 4);
      uint4 lo = make_uint4(pk[0], pk[1], pk[2], pk[3]);
      uint4 hi = make_uint4(pk[4], pk[5], pk[6], pk[7]);
      *(uint4*)(Al + r * 128 + ((sq * 32) ^ xr))      = lo;
      *(uint4*)(Al + r * 128 + ((sq * 32 + 16) ^ xr)) = hi;
    }
    __syncthreads();
    const int kgrp = lane >> 4;
    const int r15 = lane & 15;
#pragma unroll
    for (int ks = 0; ks < 2; ++ks) {
      bf16x8 a[4], b[2];
#pragma unroll
      for (int mr = 0; mr < 4; ++mr) {
        int row = wr * 64 + mr * 16 + r15;
        a[mr] = *(const bf16x8*)(Al + row * 128 +
                 ((ks * 64 + kgrp * 16) ^ ((row & 7) << 4)));
      }
#pragma unroll
      for (int nc = 0; nc < 2; ++nc) {
        int col = wc * 32 + nc * 16 + r15;
        b[nc] = *(const bf16x8*)(Bl + col * 128 +
                 ((ks * 64 + kgrp * 16) ^ ((col & 7) << 4)));
      }
#pragma unroll
      for (int mr = 0; mr < 4; ++mr)
#pragma unroll
        for (int nc = 0; nc < 2; ++nc)
          acc[mr][nc] = __builtin_amdgcn_mfma_f32_16x16x32_bf16(
              a[mr], b[nc], acc[mr][nc], 0, 0, 0);
    }
    __syncthreads();
  }
  const int r15 = lane & 15;
  const int rg4 = (lane >> 4) * 4;
#pragma unroll
  for (int mr = 0; mr < 4; ++mr) {
#pragma unroll
    for (int nc = 0; nc < 2; ++nc) {
      int row0 = bm + wr * 64 + mr * 16 + rg4;
      int colg = wc * 32 + nc * 16 + r15;
#pragma unroll
      for (int j = 0; j < 4; ++j) {
        int grow = row0 + j;
        if (grow < M) C[(size_t)grow * 64 + colg] = f2bf(acc[mr][nc][j]);
      }
    }
  }
}

// =============== radix-partition CSR build (dst-range buckets) ==============
// A: per-tile bucket histograms (LDS only, no global atomics)
__global__ __launch_bounds__(256) void k_thist(const int* __restrict__ ei,
                                               int* __restrict__ hist,
                                               int E, int NB) {
  __shared__ int lh[256];
  const int t = threadIdx.x;
  lh[t] = 0;
  __syncthreads();
  const int e0 = blockIdx.x * TS;
#pragma unroll
  for (int j = 0; j < TS / 256; ++j) {
    int e = e0 + j * 256 + t;
    if (e < E) atomicAdd(&lh[ei[E + e] >> BSH], 1);
  }
  __syncthreads();
  if (t < NB) hist[blockIdx.x * NB + t] = lh[t];
}

// B1: per-bucket exclusive scan over tiles (NT <= 512)
__global__ __launch_bounds__(256) void k_bscan1(const int* __restrict__ hist,
                                                int* __restrict__ off_rel,
                                                int* __restrict__ total,
                                                int NT, int NB) {
  __shared__ int sh[256];
  const int t = threadIdx.x;
  const int b = blockIdx.x;
  int t0 = 2 * t, t1 = 2 * t + 1;
  int v0 = (t0 < NT) ? hist[t0 * NB + b] : 0;
  int v1 = (t1 < NT) ? hist[t1 * NB + b] : 0;
  int ps = v0 + v1;
  sh[t] = ps;
  __syncthreads();
  for (int off = 1; off < 256; off <<= 1) {
    int v = (t >= off) ? sh[t - off] : 0;
    __syncthreads();
    sh[t] += v;
    __syncthreads();
  }
  int excl = sh[t] - ps;
  if (t0 < NT) off_rel[t0 * NB + b] = excl;
  if (t1 < NT) off_rel[t1 * NB + b] = excl + v0;
  if (t == 255) total[b] = sh[255];
}

// B2: exclusive scan of bucket totals -> base[NB+1]
__global__ __launch_bounds__(256) void k_bscan2(const int* __restrict__ total,
                                                int* __restrict__ base, int NB) {
  __shared__ int sh[256];
  const int t = threadIdx.x;
  int v = (t < NB) ? total[t] : 0;
  sh[t] = v;
  __syncthreads();
  for (int off = 1; off < 256; off <<= 1) {
    int x = (t >= off) ? sh[t - off] : 0;
    __syncthreads();
    sh[t] += x;
    __syncthreads();
  }
  if (t < NB) base[t] = sh[t] - v;
  if (t == NB - 1) base[NB] = sh[t];
}

// C: scatter (s,d) pairs into bucket-grouped positions
__global__ __launch_bounds__(256) void k_pscatter(const int* __restrict__ ei,
                                                  const int* __restrict__ off_rel,
                                                  const int* __restrict__ base,
                                                  int2* __restrict__ pairs,
                                                  int E, int NB) {
  __shared__ int cur[256];
  const int t = threadIdx.x;
  if (t < NB) cur[t] = base[t] + off_rel[blockIdx.x * NB + t];
  __syncthreads();
  const int e0 = blockIdx.x * TS;
#pragma unroll
  for (int j = 0; j < TS / 256; ++j) {
    int e = e0 + j * 256 + t;
    if (e < E) {
      int s = ei[e], d = ei[E + e];
      int pos = atomicAdd(&cur[d >> BSH], 1);
      pairs[pos] = make_int2(s, d);
    }
  }
}

// D: one block per bucket: local count(+self-loop) -> scan -> rowptr + col
__global__ __launch_bounds__(256) void k_bcsr(const int2* __restrict__ pairs,
                                              const int* __restrict__ base,
                                              int* __restrict__ rowptr,
                                              int* __restrict__ col,
                                              int Nn, int E, int NB) {
  __shared__ int cnt[512];
  __shared__ int cu[512];
  __shared__ int sh[256];
  const int t = threadIdx.x;
  const int b = blockIdx.x;
  const int d0 = b << BSH;
  const int dn = min(512, Nn - d0);
  const int p0 = base[b], p1 = base[b + 1];
  const int rpb = p0 + d0;   // global rowptr base (edges before + self-loops before)
  cnt[2 * t] = (2 * t < dn) ? 1 : 0;
  cnt[2 * t + 1] = (2 * t + 1 < dn) ? 1 : 0;
  __syncthreads();
  for (int i = p0 + t; i < p1; i += 256) atomicAdd(&cnt[pairs[i].y - d0], 1);
  __syncthreads();
  int a0 = cnt[2 * t], a1 = cnt[2 * t + 1];
  int ps = a0 + a1;
  sh[t] = ps;
  __syncthreads();
  for (int off = 1; off < 256; off <<= 1) {
    int v = (t >= off) ? sh[t - off] : 0;
    __syncthreads();
    sh[t] += v;
    __syncthreads();
  }
  int excl = sh[t] - ps;
  // rowptr + self-loop at segment head; cursor starts past it
#pragma unroll
  for (int u = 0; u < 2; ++u) {
    int i = 2 * t + u;
    int ex = (u == 0) ? excl : excl + a0;
    if (i < dn) {
      rowptr[d0 + i] = rpb + ex;
      col[rpb + ex] = d0 + i;   // self-loop
      cu[i] = ex + 1;
    }
  }
  if (b == NB - 1 && t == 0) rowptr[Nn] = E + Nn;
  __syncthreads();
  for (int i = p0 + t; i < p1; i += 256) {
    int2 p = pairs[i];
    int pos = atomicAdd(&cu[p.y - d0], 1);
    col[rpb + pos] = p.x;
  }
}

// ---------------- layer-1 prep: attention halves (bf16 input) ---------------
__global__ void k_prep1(const unsigned short* __restrict__ xwb,
                        const float* __restrict__ asr,
                        const float* __restrict__ adt,
                        float* __restrict__ ssrc, float* __restrict__ sdst,
                        int Nn) {
  int idx = blockIdx.x * blockDim.x + threadIdx.x;
  if (idx >= Nn * 8) return;
  int h = idx & 7;
  const uint4 v = *(const uint4*)(xwb + (size_t)(idx >> 3) * 64 + h * 8);
  float f[8];
  f[0] = __uint_as_float(v.x << 16); f[1] = __uint_as_float(v.x & 0xffff0000u);
  f[2] = __uint_as_float(v.y << 16); f[3] = __uint_as_float(v.y & 0xffff0000u);
  f[4] = __uint_as_float(v.z << 16); f[5] = __uint_as_float(v.z & 0xffff0000u);
  f[6] = __uint_as_float(v.w << 16); f[7] = __uint_as_float(v.w & 0xffff0000u);
  float ss = 0.f, sd = 0.f;
#pragma unroll
  for (int c = 0; c < 8; ++c) {
    ss += f[c] * asr[h * 8 + c];
    sd += f[c] * adt[h * 8 + c];
  }
  ssrc[idx] = ss;
  sdst[idx] = sd;
}

// ---------------- layer-1 aggregate: 4x unrolled gather, one wave/node ------
__global__ __launch_bounds__(256) void k_agg1(const int* __restrict__ rowptr,
                                              const int* __restrict__ col,
                                              const float* __restrict__ ssrc,
                                              const float* __restrict__ sdst,
                                              const unsigned short* __restrict__ xwb,
                                              const float* __restrict__ b1,
                                              float* __restrict__ h1, int Nn) {
  int wid = (blockIdx.x * 256 + threadIdx.x) >> 6;
  if (wid >= Nn) return;
  int lane = threadIdx.x & 63;
  int h = lane >> 3;
  float sd = sdst[wid * 8 + h];
  int start = rowptr[wid], end = rowptr[wid + 1];
  float den = 0.f, acc = 0.f;
  int i = start;
  for (; i + 4 <= end; i += 4) {
    int s0 = col[i], s1 = col[i + 1], s2 = col[i + 2], s3 = col[i + 3];
    float w0 = bf2f(xwb[(size_t)s0 * 64 + lane]);
    float w1 = bf2f(xwb[(size_t)s1 * 64 + lane]);
    float w2 = bf2f(xwb[(size_t)s2 * 64 + lane]);
    float w3 = bf2f(xwb[(size_t)s3 * 64 + lane]);
    float e0 = ssrc[s0 * 8 + h], e1 = ssrc[s1 * 8 + h];
    float e2 = ssrc[s2 * 8 + h], e3 = ssrc[s3 * 8 + h];
    float v0 = e0 + sd; v0 = v0 > 0.f ? v0 : NEGS * v0;
    float v1 = e1 + sd; v1 = v1 > 0.f ? v1 : NEGS * v1;
    float v2 = e2 + sd; v2 = v2 > 0.f ? v2 : NEGS * v2;
    float v3 = e3 + sd; v3 = v3 > 0.f ? v3 : NEGS * v3;
    float p0 = __expf(v0), p1 = __expf(v1), p2 = __expf(v2), p3 = __expf(v3);
    den += (p0 + p1) + (p2 + p3);
    acc = fmaf(p0, w0, acc);
    acc = fmaf(p1, w1, acc);
    acc = fmaf(p2, w2, acc);
    acc = fmaf(p3, w3, acc);
  }
  for (; i < end; ++i) {
    int s = col[i];
    float w = bf2f(xwb[(size_t)s * 64 + lane]);
    float v = ssrc[s * 8 + h] + sd;
    v = v > 0.f ? v : NEGS * v;
    float p = __expf(v);
    den += p;
    acc = fmaf(p, w, acc);
  }
  float o = acc / den + b1[lane];
  h1[(size_t)wid * 64 + lane] = o > 0.f ? o : (__expf(o) - 1.f);
}

// ---------------- GEMM2 + prep2 fused: xw2 = h1 @ W2; ssrc2/sdst2 dots ------
__global__ __launch_bounds__(256) void k_gemm2p(const float* __restrict__ h1,
                                                const float* __restrict__ W2,
                                                const float* __restrict__ asr,
                                                const float* __restrict__ adt,
                                                float* __restrict__ xw2,
                                                float* __restrict__ ssrc,
                                                float* __restrict__ sdst, int Nn) {
  __shared__ float w[64 * 16];
  int tid = threadIdx.x;
  for (int i = tid; i < 1024; i += 256) w[i] = W2[i];
  __syncthreads();
  int idx = blockIdx.x * 256 + tid;
  if (idx >= Nn * 16) return;
  int n = idx >> 4, c = idx & 15;
  const float* hr = h1 + (size_t)n * 64;
  float acc = 0.f;
#pragma unroll 8
  for (int k = 0; k < 64; ++k) acc += hr[k] * w[k * 16 + c];
  xw2[idx] = acc;
  float ssv = acc * asr[c], sdv = acc * adt[c];
#pragma unroll
  for (int off = 1; off < 16; off <<= 1) {
    ssv += __shfl_xor(ssv, off);
    sdv += __shfl_xor(sdv, off);
  }
  if (c == 0) { ssrc[n] = ssv; sdst[n] = sdv; }
}

// ---------------- layer-2 aggregate: 2x unrolled + fused log_softmax --------
__global__ __launch_bounds__(256) void k_agg2(const int* __restrict__ rowptr,
                                              const int* __restrict__ col,
                                              const float* __restrict__ ssrc,
                                              const float* __restrict__ sdst,
                                              const float* __restrict__ xw2,
                                              const float* __restrict__ b2,
                                              float* __restrict__ out, int Nn) {
  int wid = (blockIdx.x * 256 + threadIdx.x) >> 6;
  if (wid >= Nn) return;
  int lane = threadIdx.x & 63;
  int slot = lane >> 4, c = lane & 15;
  float sd = sdst[wid];
  int start = rowptr[wid], end = rowptr[wid + 1];
  float den = 0.f, acc = 0.f;
  int i = start + slot;
  for (; i + 4 < end; i += 8) {
    int s0 = col[i], s1 = col[i + 4];
    float w0 = xw2[(size_t)s0 * 16 + c];
    float w1 = xw2[(size_t)s1 * 16 + c];
    float v0 = ssrc[s0] + sd; v0 = v0 > 0.f ? v0 : NEGS * v0;
    float v1 = ssrc[s1] + sd; v1 = v1 > 0.f ? v1 : NEGS * v1;
    float p0 = __expf(v0), p1 = __expf(v1);
    den += p0 + p1;
    acc = fmaf(p0, w0, acc);
    acc = fmaf(p1, w1, acc);
  }
  if (i < end) {
    int s = col[i];
    float v = ssrc[s] + sd;
    v = v > 0.f ? v : NEGS * v;
    float p = __expf(v);
    den += p;
    acc = fmaf(p, xw2[(size_t)s * 16 + c], acc);
  }
  den += __shfl_xor(den, 16);
  den += __shfl_xor(den, 32);
  acc += __shfl_xor(acc, 16);
  acc += __shfl_xor(acc, 32);
  float o = acc / den + b2[c];
  float mx = o;
#pragma unroll
  for (int off = 1; off < 16; off <<= 1) mx = fmaxf(mx, __shfl_xor(mx, off));
  float ex = __expf(o - mx);
  float ssum = ex;
#pragma unroll
  for (int off = 1; off < 16; off <<= 1) ssum += __shfl_xor(ssum, off);
  float r = o - mx - __logf(ssum);
  if (slot == 0) out[(size_t)wid * 16 + c] = r;
}

extern "C" void kernel_launch(void* const* d_in, const int* in_sizes, int n_in,
                              void* d_out, int out_size, void* d_ws, size_t ws_size,
                              hipStream_t stream) {
  const float* x      = (const float*)d_in[0];
  const int* ei       = (const int*)d_in[1];
  const float* W1     = (const float*)d_in[2];
  const float* a_src1 = (const float*)d_in[3];
  const float* a_dst1 = (const float*)d_in[4];
  const float* b1     = (const float*)d_in[5];
  const float* W2     = (const float*)d_in[6];
  const float* a_src2 = (const float*)d_in[7];
  const float* a_dst2 = (const float*)d_in[8];
  const float* b2     = (const float*)d_in[9];

  const int F    = in_sizes[2] / 64;   // 500
  const int Nn   = in_sizes[0] / F;    // 100000
  const int E    = in_sizes[1] / 2;    // 1600000
  const int Etot = E + Nn;
  const int nck  = (F + 63) >> 6;      // K chunks of 64
  const int NB   = (Nn + 511) >> BSH;  // 196 buckets
  const int NT   = (E + TS - 1) / TS;  // 391 tiles (must be <= 512)

  // ---- workspace layout (4-byte units) ----
  float* ws = (float*)d_ws;
  unsigned short* xwb = (unsigned short*)ws;        // Nn*64 bf16 = Nn*32 units
  float* h1     = ws + (size_t)Nn * 32;             // Nn*64
  float* ssrc1  = h1 + (size_t)Nn * 64;             // Nn*8
  float* sdst1  = ssrc1 + (size_t)Nn * 8;           // Nn*8
  int* rowptr   = (int*)(sdst1 + (size_t)Nn * 8);   // Nn+1
  int* col      = rowptr + Nn + 1;                  // Etot
  unsigned short* Wb = (unsigned short*)(col + ((Etot + 7) & ~7));  // nck*4096
  // CSR-build scratch aliased over xwb/h1 (written later in the stream)
  int* hist     = (int*)ws;                         // NT*NB
  int* off_rel  = hist + (size_t)NT * NB;           // NT*NB
  int* total    = off_rel + (size_t)NT * NB;        // NB
  int* base     = total + NB;                       // NB+1
  int2* pairs   = (int2*)h1;                        // E pairs (<= Nn*32 f32)
  // layer-2 buffers reuse xwb region (dead after k_agg1)
  float* xw2    = ws;                               // Nn*16
  float* ssrc2  = xw2 + (size_t)Nn * 16;            // Nn
  float* sdst2  = ssrc2 + Nn;                       // Nn
  float* out2   = (float*)d_out;                    // Nn*16

  dim3 blk(256);

  // ---- CSR build (radix partition, XCD-local writes) ----
  k_thist<<<dim3(NT), blk, 0, stream>>>(ei, hist, E, NB);
  k_bscan1<<<dim3(NB), blk, 0, stream>>>(hist, off_rel, total, NT, NB);
  k_bscan2<<<dim3(1), blk, 0, stream>>>(total, base, NB);
  k_pscatter<<<dim3(NT), blk, 0, stream>>>(ei, off_rel, base, pairs, E, NB);
  k_bcsr<<<dim3(NB), blk, 0, stream>>>(pairs, base, rowptr, col, Nn, E, NB);

  // ---- layer 1 ----
  const int wthr = 64 * nck * 16;
  k_wcvt<<<dim3((wthr + 255) / 256), blk, 0, stream>>>(W1, Wb, F, wthr);
  k_gemm1m<<<dim3((Nn + 127) / 128), blk, 0, stream>>>(x, Wb, xwb, Nn, F, nck);
  k_prep1<<<dim3((Nn * 8 + 255) / 256), blk, 0, stream>>>(
      xwb, a_src1, a_dst1, ssrc1, sdst1, Nn);
  k_agg1<<<dim3((Nn * 64 + 255) / 256), blk, 0, stream>>>(
      rowptr, col, ssrc1, sdst1, xwb, b1, h1, Nn);

  // ---- layer 2 ----
  k_gemm2p<<<dim3((Nn * 16 + 255) / 256), blk, 0, stream>>>(
      h1, W2, a_src2, a_dst2, xw2, ssrc2, sdst2, Nn);
  k_agg2<<<dim3((Nn * 64 + 255) / 256), blk, 0, stream>>>(
      rowptr, col, ssrc2, sdst2, xw2, b2, out2, Nn);
}

// Round 8
// 242.965 us; speedup vs baseline: 20.6973x; 1.0506x over previous
//
#include <hip/hip_runtime.h>
#include <math.h>

#define NEGS 0.2f
#define BSH 9                 // bucket shift: 512 nodes per bucket
#define TS 4096               // edges per partition tile

typedef __attribute__((ext_vector_type(8))) short bf16x8;
typedef __attribute__((ext_vector_type(8))) unsigned short u16x8;
typedef __attribute__((ext_vector_type(4))) float f32x4;

__device__ __forceinline__ unsigned short f2bf(float f) {
  unsigned u = __float_as_uint(f);
  u += 0x7fffu + ((u >> 16) & 1);   // RNE
  return (unsigned short)(u >> 16);
}
__device__ __forceinline__ float bf2f(unsigned short u) {
  return __uint_as_float((unsigned)u << 16);
}

// ------- W1 -> bf16 fragment-ordered: [ck][ks][kgrp][col][8k], zero-padded --
__global__ void k_wcvt(const float* __restrict__ W1, unsigned short* __restrict__ Wb,
                       int K, int Kp) {
  int t = blockIdx.x * blockDim.x + threadIdx.x;
  if (t >= Kp * 64) return;
  int kg = t >> 6;          // 0..Kp-1
  int c = t & 63;
  float f = (kg < K) ? W1[(size_t)kg * 64 + c] : 0.f;
  // byte = ((kg>>5)*4 + ((kg>>3)&3))*1024 + c*16 + (kg&7)*2
  size_t off = ((size_t)((kg >> 5) * 4 + ((kg >> 3) & 3)) * 512) + c * 8 + (kg & 7);
  Wb[off] = f2bf(f);
}

// ------- GEMM1 (MFMA bf16, no LDS): xwb[M,64](bf16) = A[M,K] @ W1[K,64] -----
// block = 4 waves x 32 rows = 128 rows; each wave computes 32x64 via 2x4 frags
__global__ __launch_bounds__(256) void k_gemm1m(const float* __restrict__ A,
                                                const unsigned short* __restrict__ Wb,
                                                unsigned short* __restrict__ C,
                                                int M, int K, int nck) {
  const int tid = threadIdx.x;
  const int lane = tid & 63;
  const int w = tid >> 6;
  const int r15 = lane & 15;
  const int kgrp = lane >> 4;
  const int bm = blockIdx.x * 128;

  const float* Ar[2];
  int row[2];
#pragma unroll
  for (int mr = 0; mr < 2; ++mr) {
    row[mr] = bm + w * 32 + mr * 16 + r15;
    int rc = row[mr] < M ? row[mr] : (M - 1);   // clamp loads; guard stores
    Ar[mr] = A + (size_t)rc * K;
  }

  f32x4 acc[2][4] = {};

  for (int ck = 0; ck < nck; ++ck) {
#pragma unroll
    for (int ks = 0; ks < 2; ++ks) {
      const int k0 = ck * 64 + ks * 32 + kgrp * 8;
      bf16x8 af[2];
      if (ck < nck - 1) {
#pragma unroll
        for (int mr = 0; mr < 2; ++mr) {
          const float4* g = (const float4*)(Ar[mr] + k0);
          float4 f0 = g[0], f1 = g[1];
          unsigned pk[4];
          pk[0] = (unsigned)f2bf(f0.x) | ((unsigned)f2bf(f0.y) << 16);
          pk[1] = (unsigned)f2bf(f0.z) | ((unsigned)f2bf(f0.w) << 16);
          pk[2] = (unsigned)f2bf(f1.x) | ((unsigned)f2bf(f1.y) << 16);
          pk[3] = (unsigned)f2bf(f1.z) | ((unsigned)f2bf(f1.w) << 16);
          af[mr] = *(bf16x8*)pk;
        }
      } else {
#pragma unroll
        for (int mr = 0; mr < 2; ++mr) {
          float f[8];
#pragma unroll
          for (int j = 0; j < 8; ++j) {
            int kk = k0 + j;
            f[j] = (kk < K) ? Ar[mr][kk] : 0.f;
          }
          unsigned pk[4];
#pragma unroll
          for (int j = 0; j < 4; ++j)
            pk[j] = (unsigned)f2bf(f[2 * j]) | ((unsigned)f2bf(f[2 * j + 1]) << 16);
          af[mr] = *(bf16x8*)pk;
        }
      }
      // B frags: global, fragment-ordered, L2-resident
      const unsigned short* bb =
          Wb + ((size_t)((ck * 2 + ks) * 4 + kgrp) * 512) + r15 * 8;
      bf16x8 bf[4];
#pragma unroll
      for (int nc = 0; nc < 4; ++nc)
        bf[nc] = *(const bf16x8*)(bb + nc * 128);
#pragma unroll
      for (int mr = 0; mr < 2; ++mr)
#pragma unroll
        for (int nc = 0; nc < 4; ++nc)
          acc[mr][nc] = __builtin_amdgcn_mfma_f32_16x16x32_bf16(
              af[mr], bf[nc], acc[mr][nc], 0, 0, 0);
    }
  }
  const int rg4 = kgrp * 4;
#pragma unroll
  for (int mr = 0; mr < 2; ++mr) {
#pragma unroll
    for (int nc = 0; nc < 4; ++nc) {
      int row0 = bm + w * 32 + mr * 16 + rg4;
      int colg = nc * 16 + r15;
#pragma unroll
      for (int j = 0; j < 4; ++j) {
        int grow = row0 + j;
        if (grow < M) C[(size_t)grow * 64 + colg] = f2bf(acc[mr][nc][j]);
      }
    }
  }
}

// =============== radix-partition CSR build (dst-range buckets) ==============
__global__ __launch_bounds__(256) void k_thist(const int* __restrict__ ei,
                                               int* __restrict__ hist,
                                               int E, int NB) {
  __shared__ int lh[256];
  const int t = threadIdx.x;
  lh[t] = 0;
  __syncthreads();
  const int e0 = blockIdx.x * TS;
#pragma unroll
  for (int j = 0; j < TS / 256; ++j) {
    int e = e0 + j * 256 + t;
    if (e < E) atomicAdd(&lh[ei[E + e] >> BSH], 1);
  }
  __syncthreads();
  if (t < NB) hist[blockIdx.x * NB + t] = lh[t];
}

__global__ __launch_bounds__(256) void k_bscan1(const int* __restrict__ hist,
                                                int* __restrict__ off_rel,
                                                int* __restrict__ total,
                                                int NT, int NB) {
  __shared__ int sh[256];
  const int t = threadIdx.x;
  const int b = blockIdx.x;
  int t0 = 2 * t, t1 = 2 * t + 1;
  int v0 = (t0 < NT) ? hist[t0 * NB + b] : 0;
  int v1 = (t1 < NT) ? hist[t1 * NB + b] : 0;
  int ps = v0 + v1;
  sh[t] = ps;
  __syncthreads();
  for (int off = 1; off < 256; off <<= 1) {
    int v = (t >= off) ? sh[t - off] : 0;
    __syncthreads();
    sh[t] += v;
    __syncthreads();
  }
  int excl = sh[t] - ps;
  if (t0 < NT) off_rel[t0 * NB + b] = excl;
  if (t1 < NT) off_rel[t1 * NB + b] = excl + v0;
  if (t == 255) total[b] = sh[255];
}

__global__ __launch_bounds__(256) void k_bscan2(const int* __restrict__ total,
                                                int* __restrict__ base, int NB) {
  __shared__ int sh[256];
  const int t = threadIdx.x;
  int v = (t < NB) ? total[t] : 0;
  sh[t] = v;
  __syncthreads();
  for (int off = 1; off < 256; off <<= 1) {
    int x = (t >= off) ? sh[t - off] : 0;
    __syncthreads();
    sh[t] += x;
    __syncthreads();
  }
  if (t < NB) base[t] = sh[t] - v;
  if (t == NB - 1) base[NB] = sh[t];
}

__global__ __launch_bounds__(256) void k_pscatter(const int* __restrict__ ei,
                                                  const int* __restrict__ off_rel,
                                                  const int* __restrict__ base,
                                                  int2* __restrict__ pairs,
                                                  int E, int NB) {
  __shared__ int cur[256];
  const int t = threadIdx.x;
  if (t < NB) cur[t] = base[t] + off_rel[blockIdx.x * NB + t];
  __syncthreads();
  const int e0 = blockIdx.x * TS;
#pragma unroll
  for (int j = 0; j < TS / 256; ++j) {
    int e = e0 + j * 256 + t;
    if (e < E) {
      int s = ei[e], d = ei[E + e];
      int pos = atomicAdd(&cur[d >> BSH], 1);
      pairs[pos] = make_int2(s, d);
    }
  }
}

__global__ __launch_bounds__(256) void k_bcsr(const int2* __restrict__ pairs,
                                              const int* __restrict__ base,
                                              int* __restrict__ rowptr,
                                              int* __restrict__ col,
                                              int Nn, int E, int NB) {
  __shared__ int cnt[512];
  __shared__ int cu[512];
  __shared__ int sh[256];
  const int t = threadIdx.x;
  const int b = blockIdx.x;
  const int d0 = b << BSH;
  const int dn = min(512, Nn - d0);
  const int p0 = base[b], p1 = base[b + 1];
  const int rpb = p0 + d0;
  cnt[2 * t] = (2 * t < dn) ? 1 : 0;
  cnt[2 * t + 1] = (2 * t + 1 < dn) ? 1 : 0;
  __syncthreads();
  for (int i = p0 + t; i < p1; i += 256) atomicAdd(&cnt[pairs[i].y - d0], 1);
  __syncthreads();
  int a0 = cnt[2 * t], a1 = cnt[2 * t + 1];
  int ps = a0 + a1;
  sh[t] = ps;
  __syncthreads();
  for (int off = 1; off < 256; off <<= 1) {
    int v = (t >= off) ? sh[t - off] : 0;
    __syncthreads();
    sh[t] += v;
    __syncthreads();
  }
  int excl = sh[t] - ps;
#pragma unroll
  for (int u = 0; u < 2; ++u) {
    int i = 2 * t + u;
    int ex = (u == 0) ? excl : excl + a0;
    if (i < dn) {
      rowptr[d0 + i] = rpb + ex;
      col[rpb + ex] = d0 + i;   // self-loop
      cu[i] = ex + 1;
    }
  }
  if (b == NB - 1 && t == 0) rowptr[Nn] = E + Nn;
  __syncthreads();
  for (int i = p0 + t; i < p1; i += 256) {
    int2 p = pairs[i];
    int pos = atomicAdd(&cu[p.y - d0], 1);
    col[rpb + pos] = p.x;
  }
}

// ---------------- layer-1 prep: attention halves (bf16 input) ---------------
__global__ void k_prep1(const unsigned short* __restrict__ xwb,
                        const float* __restrict__ asr,
                        const float* __restrict__ adt,
                        float* __restrict__ ssrc, float* __restrict__ sdst,
                        int Nn) {
  int idx = blockIdx.x * blockDim.x + threadIdx.x;
  if (idx >= Nn * 8) return;
  int h = idx & 7;
  const uint4 v = *(const uint4*)(xwb + (size_t)(idx >> 3) * 64 + h * 8);
  float f[8];
  f[0] = __uint_as_float(v.x << 16); f[1] = __uint_as_float(v.x & 0xffff0000u);
  f[2] = __uint_as_float(v.y << 16); f[3] = __uint_as_float(v.y & 0xffff0000u);
  f[4] = __uint_as_float(v.z << 16); f[5] = __uint_as_float(v.z & 0xffff0000u);
  f[6] = __uint_as_float(v.w << 16); f[7] = __uint_as_float(v.w & 0xffff0000u);
  float ss = 0.f, sd = 0.f;
#pragma unroll
  for (int c = 0; c < 8; ++c) {
    ss += f[c] * asr[h * 8 + c];
    sd += f[c] * adt[h * 8 + c];
  }
  ssrc[idx] = ss;
  sdst[idx] = sd;
}

// ------- layer-1 aggregate: 8 edges/iter, lane = slot(8) x head(8) ----------
__global__ __launch_bounds__(256) void k_agg1(const int* __restrict__ rowptr,
                                              const int* __restrict__ col,
                                              const float* __restrict__ ssrc,
                                              const float* __restrict__ sdst,
                                              const unsigned short* __restrict__ xwb,
                                              const float* __restrict__ b1,
                                              float* __restrict__ h1, int Nn) {
  int wid = (blockIdx.x * 256 + threadIdx.x) >> 6;
  if (wid >= Nn) return;
  int lane = threadIdx.x & 63;
  int slot = lane >> 3;     // edge slot 0..7
  int chg = lane & 7;       // head / channel group 0..7
  float sd = sdst[wid * 8 + chg];
  int start = rowptr[wid], end = rowptr[wid + 1];
  float den = 0.f;
  float acc[8] = {};
  for (int it = start; it < end; it += 8) {
    int idx = it + slot;
    bool ok = idx < end;
    int s = col[ok ? idx : start];
    u16x8 pv = *(const u16x8*)(xwb + (size_t)s * 64 + chg * 8);  // 16B coalesced
    float v = ssrc[s * 8 + chg] + sd;
    v = v > 0.f ? v : NEGS * v;
    float p = ok ? __expf(v) : 0.f;
    den += p;
#pragma unroll
    for (int j = 0; j < 8; ++j) acc[j] = fmaf(p, bf2f(pv[j]), acc[j]);
  }
  // cross-slot reduce (lanes sharing chg): strides 8,16,32
#pragma unroll
  for (int off = 8; off < 64; off <<= 1) {
    den += __shfl_xor(den, off);
#pragma unroll
    for (int j = 0; j < 8; ++j) acc[j] += __shfl_xor(acc[j], off);
  }
  if (slot == 0) {
    float inv = 1.f / den;
    float o[8];
#pragma unroll
    for (int j = 0; j < 8; ++j) {
      float v = acc[j] * inv + b1[chg * 8 + j];
      o[j] = v > 0.f ? v : (__expf(v) - 1.f);
    }
    float* dst = h1 + (size_t)wid * 64 + chg * 8;
#pragma unroll
    for (int j = 0; j < 8; ++j) dst[j] = o[j];
  }
}

// ---------------- GEMM2 + prep2 fused: xw2 = h1 @ W2; ssrc2/sdst2 dots ------
__global__ __launch_bounds__(256) void k_gemm2p(const float* __restrict__ h1,
                                                const float* __restrict__ W2,
                                                const float* __restrict__ asr,
                                                const float* __restrict__ adt,
                                                float* __restrict__ xw2,
                                                float* __restrict__ ssrc,
                                                float* __restrict__ sdst, int Nn) {
  __shared__ float w[64 * 16];
  int tid = threadIdx.x;
  for (int i = tid; i < 1024; i += 256) w[i] = W2[i];
  __syncthreads();
  int idx = blockIdx.x * 256 + tid;
  if (idx >= Nn * 16) return;
  int n = idx >> 4, c = idx & 15;
  const float* hr = h1 + (size_t)n * 64;
  float acc = 0.f;
#pragma unroll 8
  for (int k = 0; k < 64; ++k) acc += hr[k] * w[k * 16 + c];
  xw2[idx] = acc;
  float ssv = acc * asr[c], sdv = acc * adt[c];
#pragma unroll
  for (int off = 1; off < 16; off <<= 1) {
    ssv += __shfl_xor(ssv, off);
    sdv += __shfl_xor(sdv, off);
  }
  if (c == 0) { ssrc[n] = ssv; sdst[n] = sdv; }
}

// ---------------- layer-2 aggregate: 2x unrolled + fused log_softmax --------
__global__ __launch_bounds__(256) void k_agg2(const int* __restrict__ rowptr,
                                              const int* __restrict__ col,
                                              const float* __restrict__ ssrc,
                                              const float* __restrict__ sdst,
                                              const float* __restrict__ xw2,
                                              const float* __restrict__ b2,
                                              float* __restrict__ out, int Nn) {
  int wid = (blockIdx.x * 256 + threadIdx.x) >> 6;
  if (wid >= Nn) return;
  int lane = threadIdx.x & 63;
  int slot = lane >> 4, c = lane & 15;
  float sd = sdst[wid];
  int start = rowptr[wid], end = rowptr[wid + 1];
  float den = 0.f, acc = 0.f;
  int i = start + slot;
  for (; i + 4 < end; i += 8) {
    int s0 = col[i], s1 = col[i + 4];
    float w0 = xw2[(size_t)s0 * 16 + c];
    float w1 = xw2[(size_t)s1 * 16 + c];
    float v0 = ssrc[s0] + sd; v0 = v0 > 0.f ? v0 : NEGS * v0;
    float v1 = ssrc[s1] + sd; v1 = v1 > 0.f ? v1 : NEGS * v1;
    float p0 = __expf(v0), p1 = __expf(v1);
    den += p0 + p1;
    acc = fmaf(p0, w0, acc);
    acc = fmaf(p1, w1, acc);
  }
  if (i < end) {
    int s = col[i];
    float v = ssrc[s] + sd;
    v = v > 0.f ? v : NEGS * v;
    float p = __expf(v);
    den += p;
    acc = fmaf(p, xw2[(size_t)s * 16 + c], acc);
  }
  den += __shfl_xor(den, 16);
  den += __shfl_xor(den, 32);
  acc += __shfl_xor(acc, 16);
  acc += __shfl_xor(acc, 32);
  float o = acc / den + b2[c];
  float mx = o;
#pragma unroll
  for (int off = 1; off < 16; off <<= 1) mx = fmaxf(mx, __shfl_xor(mx, off));
  float ex = __expf(o - mx);
  float ssum = ex;
#pragma unroll
  for (int off = 1; off < 16; off <<= 1) ssum += __shfl_xor(ssum, off);
  float r = o - mx - __logf(ssum);
  if (slot == 0) out[(size_t)wid * 16 + c] = r;
}

extern "C" void kernel_launch(void* const* d_in, const int* in_sizes, int n_in,
                              void* d_out, int out_size, void* d_ws, size_t ws_size,
                              hipStream_t stream) {
  const float* x      = (const float*)d_in[0];
  const int* ei       = (const int*)d_in[1];
  const float* W1     = (const float*)d_in[2];
  const float* a_src1 = (const float*)d_in[3];
  const float* a_dst1 = (const float*)d_in[4];
  const float* b1     = (const float*)d_in[5];
  const float* W2     = (const float*)d_in[6];
  const float* a_src2 = (const float*)d_in[7];
  const float* a_dst2 = (const float*)d_in[8];
  const float* b2     = (const float*)d_in[9];

  const int F    = in_sizes[2] / 64;   // 500
  const int Nn   = in_sizes[0] / F;    // 100000
  const int E    = in_sizes[1] / 2;    // 1600000
  const int Etot = E + Nn;
  const int nck  = (F + 63) >> 6;      // K chunks of 64
  const int Kp   = nck * 64;           // padded K
  const int NB   = (Nn + 511) >> BSH;  // buckets
  const int NT   = (E + TS - 1) / TS;  // partition tiles (<= 512)

  // ---- workspace layout (4-byte units) ----
  float* ws = (float*)d_ws;
  unsigned short* xwb = (unsigned short*)ws;        // Nn*64 bf16 = Nn*32 units
  float* h1     = ws + (size_t)Nn * 32;             // Nn*64
  float* ssrc1  = h1 + (size_t)Nn * 64;             // Nn*8
  float* sdst1  = ssrc1 + (size_t)Nn * 8;           // Nn*8
  int* rowptr   = (int*)(sdst1 + (size_t)Nn * 8);   // Nn+1
  int* col      = rowptr + Nn + 1;                  // Etot
  unsigned short* Wb = (unsigned short*)(col + ((Etot + 7) & ~7));  // Kp*64 bf16
  // CSR-build scratch aliased over xwb/h1 (written later in the stream)
  int* hist     = (int*)ws;                         // NT*NB
  int* off_rel  = hist + (size_t)NT * NB;           // NT*NB
  int* total    = off_rel + (size_t)NT * NB;        // NB
  int* base     = total + NB;                       // NB+1
  int2* pairs   = (int2*)h1;                        // E pairs
  // layer-2 buffers reuse xwb region (dead after k_agg1)
  float* xw2    = ws;                               // Nn*16
  float* ssrc2  = xw2 + (size_t)Nn * 16;            // Nn
  float* sdst2  = ssrc2 + Nn;                       // Nn
  float* out2   = (float*)d_out;                    // Nn*16

  dim3 blk(256);

  // ---- CSR build (radix partition, XCD-local writes) ----
  k_thist<<<dim3(NT), blk, 0, stream>>>(ei, hist, E, NB);
  k_bscan1<<<dim3(NB), blk, 0, stream>>>(hist, off_rel, total, NT, NB);
  k_bscan2<<<dim3(1), blk, 0, stream>>>(total, base, NB);
  k_pscatter<<<dim3(NT), blk, 0, stream>>>(ei, off_rel, base, pairs, E, NB);
  k_bcsr<<<dim3(NB), blk, 0, stream>>>(pairs, base, rowptr, col, Nn, E, NB);

  // ---- layer 1 ----
  k_wcvt<<<dim3((Kp * 64 + 255) / 256), blk, 0, stream>>>(W1, Wb, F, Kp);
  k_gemm1m<<<dim3((Nn + 127) / 128), blk, 0, stream>>>(x, Wb, xwb, Nn, F, nck);
  k_prep1<<<dim3((Nn * 8 + 255) / 256), blk, 0, stream>>>(
      xwb, a_src1, a_dst1, ssrc1, sdst1, Nn);
  k_agg1<<<dim3((Nn * 64 + 255) / 256), blk, 0, stream>>>(
      rowptr, col, ssrc1, sdst1, xwb, b1, h1, Nn);

  // ---- layer 2 ----
  k_gemm2p<<<dim3((Nn * 16 + 255) / 256), blk, 0, stream>>>(
      h1, W2, a_src2, a_dst2, xw2, ssrc2, sdst2, Nn);
  k_agg2<<<dim3((Nn * 64 + 255) / 256), blk, 0, stream>>>(
      rowptr, col, ssrc2, sdst2, xw2, b2, out2, Nn);
}

// Round 9
// 239.010 us; speedup vs baseline: 21.0397x; 1.0165x over previous
//
#include <hip/hip_runtime.h>
#include <math.h>

#define NEGS 0.2f
#define BSH 9                 // bucket shift: 512 nodes per bucket
#define TS 4096               // edges per partition tile

typedef __attribute__((ext_vector_type(8))) short bf16x8;
typedef __attribute__((ext_vector_type(8))) unsigned short u16x8;
typedef __attribute__((ext_vector_type(4))) float f32x4;

__device__ __forceinline__ unsigned short f2bf(float f) {
  unsigned u = __float_as_uint(f);
  u += 0x7fffu + ((u >> 16) & 1);   // RNE
  return (unsigned short)(u >> 16);
}
__device__ __forceinline__ float bf2f(unsigned short u) {
  return __uint_as_float((unsigned)u << 16);
}

// ------- W1 -> bf16 fragment-ordered: [ck][ks][kgrp][col][8k], zero-padded --
__global__ void k_wcvt(const float* __restrict__ W1, unsigned short* __restrict__ Wb,
                       int K, int Kp) {
  int t = blockIdx.x * blockDim.x + threadIdx.x;
  if (t >= Kp * 64) return;
  int kg = t >> 6;          // 0..Kp-1
  int c = t & 63;
  float f = (kg < K) ? W1[(size_t)kg * 64 + c] : 0.f;
  size_t off = ((size_t)((kg >> 5) * 4 + ((kg >> 3) & 3)) * 512) + c * 8 + (kg & 7);
  Wb[off] = f2bf(f);
}

// ------- GEMM1 (MFMA bf16, no LDS): xwb[M,64](bf16) = A[M,K] @ W1[K,64] -----
// block = 4 waves x 16 rows = 64 rows; each wave computes 16x64 via 1x4 frags
__global__ __launch_bounds__(256) void k_gemm1m(const float* __restrict__ A,
                                                const unsigned short* __restrict__ Wb,
                                                unsigned short* __restrict__ C,
                                                int M, int K, int nck) {
  const int tid = threadIdx.x;
  const int lane = tid & 63;
  const int w = tid >> 6;
  const int r15 = lane & 15;
  const int kgrp = lane >> 4;
  const int bm = blockIdx.x * 64;

  const int row = bm + w * 16 + r15;
  const float* Ar = A + (size_t)(row < M ? row : (M - 1)) * K;

  f32x4 acc[4] = {};

  for (int ck = 0; ck < nck; ++ck) {
#pragma unroll
    for (int ks = 0; ks < 2; ++ks) {
      const int k0 = ck * 64 + ks * 32 + kgrp * 8;
      bf16x8 af;
      if (ck < nck - 1) {
        const float4* g = (const float4*)(Ar + k0);
        float4 f0 = g[0], f1 = g[1];
        unsigned pk[4];
        pk[0] = (unsigned)f2bf(f0.x) | ((unsigned)f2bf(f0.y) << 16);
        pk[1] = (unsigned)f2bf(f0.z) | ((unsigned)f2bf(f0.w) << 16);
        pk[2] = (unsigned)f2bf(f1.x) | ((unsigned)f2bf(f1.y) << 16);
        pk[3] = (unsigned)f2bf(f1.z) | ((unsigned)f2bf(f1.w) << 16);
        af = *(bf16x8*)pk;
      } else {
        float f[8];
#pragma unroll
        for (int j = 0; j < 8; ++j) {
          int kk = k0 + j;
          f[j] = (kk < K) ? Ar[kk] : 0.f;
        }
        unsigned pk[4];
#pragma unroll
        for (int j = 0; j < 4; ++j)
          pk[j] = (unsigned)f2bf(f[2 * j]) | ((unsigned)f2bf(f[2 * j + 1]) << 16);
        af = *(bf16x8*)pk;
      }
      const unsigned short* bb =
          Wb + ((size_t)((ck * 2 + ks) * 4 + kgrp) * 512) + r15 * 8;
      bf16x8 bf[4];
#pragma unroll
      for (int nc = 0; nc < 4; ++nc)
        bf[nc] = *(const bf16x8*)(bb + nc * 128);
#pragma unroll
      for (int nc = 0; nc < 4; ++nc)
        acc[nc] = __builtin_amdgcn_mfma_f32_16x16x32_bf16(af, bf[nc], acc[nc], 0, 0, 0);
    }
  }
  const int rg4 = kgrp * 4;
#pragma unroll
  for (int nc = 0; nc < 4; ++nc) {
    int row0 = bm + w * 16 + rg4;
    int colg = nc * 16 + r15;
#pragma unroll
    for (int j = 0; j < 4; ++j) {
      int grow = row0 + j;
      if (grow < M) C[(size_t)grow * 64 + colg] = f2bf(acc[nc][j]);
    }
  }
}

// =============== radix-partition CSR build (dst-range buckets) ==============
__global__ __launch_bounds__(256) void k_thist(const int* __restrict__ ei,
                                               int* __restrict__ hist,
                                               int E, int NB) {
  __shared__ int lh[256];
  const int t = threadIdx.x;
  lh[t] = 0;
  __syncthreads();
  const int e0 = blockIdx.x * TS;
#pragma unroll
  for (int j = 0; j < TS / 256; ++j) {
    int e = e0 + j * 256 + t;
    if (e < E) atomicAdd(&lh[ei[E + e] >> BSH], 1);
  }
  __syncthreads();
  if (t < NB) hist[blockIdx.x * NB + t] = lh[t];
}

__global__ __launch_bounds__(256) void k_bscan1(const int* __restrict__ hist,
                                                int* __restrict__ off_rel,
                                                int* __restrict__ total,
                                                int NT, int NB) {
  __shared__ int sh[256];
  const int t = threadIdx.x;
  const int b = blockIdx.x;
  int t0 = 2 * t, t1 = 2 * t + 1;
  int v0 = (t0 < NT) ? hist[t0 * NB + b] : 0;
  int v1 = (t1 < NT) ? hist[t1 * NB + b] : 0;
  int ps = v0 + v1;
  sh[t] = ps;
  __syncthreads();
  for (int off = 1; off < 256; off <<= 1) {
    int v = (t >= off) ? sh[t - off] : 0;
    __syncthreads();
    sh[t] += v;
    __syncthreads();
  }
  int excl = sh[t] - ps;
  if (t0 < NT) off_rel[t0 * NB + b] = excl;
  if (t1 < NT) off_rel[t1 * NB + b] = excl + v0;
  if (t == 255) total[b] = sh[255];
}

// C: scatter packed (dloc<<23 | s) into bucket-grouped positions
__global__ __launch_bounds__(256) void k_pscatter(const int* __restrict__ ei,
                                                  const int* __restrict__ off_rel,
                                                  const int* __restrict__ total,
                                                  unsigned* __restrict__ pairs,
                                                  int E, int NB) {
  __shared__ int cur[256];
  __shared__ int sb[256];
  const int t = threadIdx.x;
  int v = (t < NB) ? total[t] : 0;
  sb[t] = v;
  __syncthreads();
  for (int off = 1; off < 256; off <<= 1) {
    int x = (t >= off) ? sb[t - off] : 0;
    __syncthreads();
    sb[t] += x;
    __syncthreads();
  }
  if (t < NB) cur[t] = (sb[t] - v) + off_rel[blockIdx.x * NB + t];
  __syncthreads();
  const int e0 = blockIdx.x * TS;
#pragma unroll
  for (int j = 0; j < TS / 256; ++j) {
    int e = e0 + j * 256 + t;
    if (e < E) {
      int s = ei[e], d = ei[E + e];
      int pos = atomicAdd(&cur[d >> BSH], 1);
      pairs[pos] = ((unsigned)(d & ((1 << BSH) - 1)) << 23) | (unsigned)s;
    }
  }
}

// D: one block per bucket: local count(+self-loop) -> scan -> rowptr + col
__global__ __launch_bounds__(256) void k_bcsr(const unsigned* __restrict__ pairs,
                                              const int* __restrict__ total,
                                              int* __restrict__ rowptr,
                                              int* __restrict__ col,
                                              int Nn, int E, int NB) {
  __shared__ int cnt[512];
  __shared__ int cu[512];
  __shared__ int sh[256];
  __shared__ int P0, P1;
  const int t = threadIdx.x;
  const int b = blockIdx.x;
  const int d0 = b << BSH;
  const int dn = min(1 << BSH, Nn - d0);
  // local scan of bucket totals -> p0/p1
  {
    int v = (t < NB) ? total[t] : 0;
    sh[t] = v;
    __syncthreads();
    for (int off = 1; off < 256; off <<= 1) {
      int x = (t >= off) ? sh[t - off] : 0;
      __syncthreads();
      sh[t] += x;
      __syncthreads();
    }
    if (t == b) { P0 = sh[t] - v; P1 = sh[t]; }
    __syncthreads();
  }
  const int p0 = P0, p1 = P1;
  const int rpb = p0 + d0;
  cnt[2 * t] = (2 * t < dn) ? 1 : 0;
  cnt[2 * t + 1] = (2 * t + 1 < dn) ? 1 : 0;
  __syncthreads();
  for (int i = p0 + t; i < p1; i += 256) atomicAdd(&cnt[pairs[i] >> 23], 1);
  __syncthreads();
  int a0 = cnt[2 * t], a1 = cnt[2 * t + 1];
  int ps = a0 + a1;
  sh[t] = ps;
  __syncthreads();
  for (int off = 1; off < 256; off <<= 1) {
    int v = (t >= off) ? sh[t - off] : 0;
    __syncthreads();
    sh[t] += v;
    __syncthreads();
  }
  int excl = sh[t] - ps;
#pragma unroll
  for (int u = 0; u < 2; ++u) {
    int i = 2 * t + u;
    int ex = (u == 0) ? excl : excl + a0;
    if (i < dn) {
      rowptr[d0 + i] = rpb + ex;
      col[rpb + ex] = d0 + i;   // self-loop
      cu[i] = ex + 1;
    }
  }
  if (b == NB - 1 && t == 0) rowptr[Nn] = E + Nn;
  __syncthreads();
  for (int i = p0 + t; i < p1; i += 256) {
    unsigned p = pairs[i];
    int pos = atomicAdd(&cu[p >> 23], 1);
    col[rpb + pos] = (int)(p & 0x7fffffu);
  }
}

// ---------------- layer-1 prep: attention halves (bf16 input) ---------------
__global__ void k_prep1(const unsigned short* __restrict__ xwb,
                        const float* __restrict__ asr,
                        const float* __restrict__ adt,
                        float* __restrict__ ssrc, float* __restrict__ sdst,
                        int Nn) {
  int idx = blockIdx.x * blockDim.x + threadIdx.x;
  if (idx >= Nn * 8) return;
  int h = idx & 7;
  const uint4 v = *(const uint4*)(xwb + (size_t)(idx >> 3) * 64 + h * 8);
  float f[8];
  f[0] = __uint_as_float(v.x << 16); f[1] = __uint_as_float(v.x & 0xffff0000u);
  f[2] = __uint_as_float(v.y << 16); f[3] = __uint_as_float(v.y & 0xffff0000u);
  f[4] = __uint_as_float(v.z << 16); f[5] = __uint_as_float(v.z & 0xffff0000u);
  f[6] = __uint_as_float(v.w << 16); f[7] = __uint_as_float(v.w & 0xffff0000u);
  float ss = 0.f, sd = 0.f;
#pragma unroll
  for (int c = 0; c < 8; ++c) {
    ss += f[c] * asr[h * 8 + c];
    sd += f[c] * adt[h * 8 + c];
  }
  ssrc[idx] = ss;
  sdst[idx] = sd;
}

// ------- layer-1 aggregate: 8 edges/iter, lane = slot(8) x head(8) ----------
__global__ __launch_bounds__(256) void k_agg1(const int* __restrict__ rowptr,
                                              const int* __restrict__ col,
                                              const float* __restrict__ ssrc,
                                              const float* __restrict__ sdst,
                                              const unsigned short* __restrict__ xwb,
                                              const float* __restrict__ b1,
                                              float* __restrict__ h1, int Nn) {
  int wid = (blockIdx.x * 256 + threadIdx.x) >> 6;
  if (wid >= Nn) return;
  int lane = threadIdx.x & 63;
  int slot = lane >> 3;     // edge slot 0..7
  int chg = lane & 7;       // head / channel group 0..7
  float sd = sdst[wid * 8 + chg];
  int start = rowptr[wid], end = rowptr[wid + 1];
  float den = 0.f;
  float acc[8] = {};
  for (int it = start; it < end; it += 8) {
    int idx = it + slot;
    bool ok = idx < end;
    int s = col[ok ? idx : start];
    u16x8 pv = *(const u16x8*)(xwb + (size_t)s * 64 + chg * 8);  // 16B coalesced
    float v = ssrc[s * 8 + chg] + sd;
    v = v > 0.f ? v : NEGS * v;
    float p = ok ? __expf(v) : 0.f;
    den += p;
#pragma unroll
    for (int j = 0; j < 8; ++j) acc[j] = fmaf(p, bf2f(pv[j]), acc[j]);
  }
#pragma unroll
  for (int off = 8; off < 64; off <<= 1) {
    den += __shfl_xor(den, off);
#pragma unroll
    for (int j = 0; j < 8; ++j) acc[j] += __shfl_xor(acc[j], off);
  }
  if (slot == 0) {
    float inv = 1.f / den;
    float o[8];
#pragma unroll
    for (int j = 0; j < 8; ++j) {
      float v = acc[j] * inv + b1[chg * 8 + j];
      o[j] = v > 0.f ? v : (__expf(v) - 1.f);
    }
    float* dst = h1 + (size_t)wid * 64 + chg * 8;
#pragma unroll
    for (int j = 0; j < 8; ++j) dst[j] = o[j];
  }
}

// ---------------- GEMM2 + prep2 fused: xw2 = h1 @ W2; ssrc2/sdst2 dots ------
__global__ __launch_bounds__(256) void k_gemm2p(const float* __restrict__ h1,
                                                const float* __restrict__ W2,
                                                const float* __restrict__ asr,
                                                const float* __restrict__ adt,
                                                float* __restrict__ xw2,
                                                float* __restrict__ ssrc,
                                                float* __restrict__ sdst, int Nn) {
  __shared__ float w[64 * 16];
  int tid = threadIdx.x;
  for (int i = tid; i < 1024; i += 256) w[i] = W2[i];
  __syncthreads();
  int idx = blockIdx.x * 256 + tid;
  if (idx >= Nn * 16) return;
  int n = idx >> 4, c = idx & 15;
  const float* hr = h1 + (size_t)n * 64;
  float acc = 0.f;
#pragma unroll 8
  for (int k = 0; k < 64; ++k) acc += hr[k] * w[k * 16 + c];
  xw2[idx] = acc;
  float ssv = acc * asr[c], sdv = acc * adt[c];
#pragma unroll
  for (int off = 1; off < 16; off <<= 1) {
    ssv += __shfl_xor(ssv, off);
    sdv += __shfl_xor(sdv, off);
  }
  if (c == 0) { ssrc[n] = ssv; sdst[n] = sdv; }
}

// ---------------- layer-2 aggregate: 2x unrolled + fused log_softmax --------
__global__ __launch_bounds__(256) void k_agg2(const int* __restrict__ rowptr,
                                              const int* __restrict__ col,
                                              const float* __restrict__ ssrc,
                                              const float* __restrict__ sdst,
                                              const float* __restrict__ xw2,
                                              const float* __restrict__ b2,
                                              float* __restrict__ out, int Nn) {
  int wid = (blockIdx.x * 256 + threadIdx.x) >> 6;
  if (wid >= Nn) return;
  int lane = threadIdx.x & 63;
  int slot = lane >> 4, c = lane & 15;
  float sd = sdst[wid];
  int start = rowptr[wid], end = rowptr[wid + 1];
  float den = 0.f, acc = 0.f;
  int i = start + slot;
  for (; i + 4 < end; i += 8) {
    int s0 = col[i], s1 = col[i + 4];
    float w0 = xw2[(size_t)s0 * 16 + c];
    float w1 = xw2[(size_t)s1 * 16 + c];
    float v0 = ssrc[s0] + sd; v0 = v0 > 0.f ? v0 : NEGS * v0;
    float v1 = ssrc[s1] + sd; v1 = v1 > 0.f ? v1 : NEGS * v1;
    float p0 = __expf(v0), p1 = __expf(v1);
    den += p0 + p1;
    acc = fmaf(p0, w0, acc);
    acc = fmaf(p1, w1, acc);
  }
  if (i < end) {
    int s = col[i];
    float v = ssrc[s] + sd;
    v = v > 0.f ? v : NEGS * v;
    float p = __expf(v);
    den += p;
    acc = fmaf(p, xw2[(size_t)s * 16 + c], acc);
  }
  den += __shfl_xor(den, 16);
  den += __shfl_xor(den, 32);
  acc += __shfl_xor(acc, 16);
  acc += __shfl_xor(acc, 32);
  float o = acc / den + b2[c];
  float mx = o;
#pragma unroll
  for (int off = 1; off < 16; off <<= 1) mx = fmaxf(mx, __shfl_xor(mx, off));
  float ex = __expf(o - mx);
  float ssum = ex;
#pragma unroll
  for (int off = 1; off < 16; off <<= 1) ssum += __shfl_xor(ssum, off);
  float r = o - mx - __logf(ssum);
  if (slot == 0) out[(size_t)wid * 16 + c] = r;
}

extern "C" void kernel_launch(void* const* d_in, const int* in_sizes, int n_in,
                              void* d_out, int out_size, void* d_ws, size_t ws_size,
                              hipStream_t stream) {
  const float* x      = (const float*)d_in[0];
  const int* ei       = (const int*)d_in[1];
  const float* W1     = (const float*)d_in[2];
  const float* a_src1 = (const float*)d_in[3];
  const float* a_dst1 = (const float*)d_in[4];
  const float* b1     = (const float*)d_in[5];
  const float* W2     = (const float*)d_in[6];
  const float* a_src2 = (const float*)d_in[7];
  const float* a_dst2 = (const float*)d_in[8];
  const float* b2     = (const float*)d_in[9];

  const int F    = in_sizes[2] / 64;   // 500
  const int Nn   = in_sizes[0] / F;    // 100000
  const int E    = in_sizes[1] / 2;    // 1600000
  const int Etot = E + Nn;
  const int nck  = (F + 63) >> 6;      // K chunks of 64
  const int Kp   = nck * 64;           // padded K
  const int NB   = (Nn + (1 << BSH) - 1) >> BSH;  // buckets (<=256)
  const int NT   = (E + TS - 1) / TS;  // partition tiles (<= 512)

  // ---- workspace layout (4-byte units) ----
  float* ws = (float*)d_ws;
  unsigned short* xwb = (unsigned short*)ws;        // Nn*64 bf16 = Nn*32 units
  float* h1     = ws + (size_t)Nn * 32;             // Nn*64
  float* ssrc1  = h1 + (size_t)Nn * 64;             // Nn*8
  float* sdst1  = ssrc1 + (size_t)Nn * 8;           // Nn*8
  int* rowptr   = (int*)(sdst1 + (size_t)Nn * 8);   // Nn+1
  int* col      = rowptr + Nn + 1;                  // Etot
  unsigned short* Wb = (unsigned short*)(col + ((Etot + 7) & ~7));  // Kp*64 bf16
  // CSR-build scratch aliased over xwb/h1 (written later in the stream)
  int* hist     = (int*)ws;                         // NT*NB
  int* off_rel  = hist + (size_t)NT * NB;           // NT*NB
  int* total    = off_rel + (size_t)NT * NB;        // NB
  unsigned* pairs = (unsigned*)h1;                  // E packed u32
  // layer-2 buffers reuse xwb region (dead after k_agg1)
  float* xw2    = ws;                               // Nn*16
  float* ssrc2  = xw2 + (size_t)Nn * 16;            // Nn
  float* sdst2  = ssrc2 + Nn;                       // Nn
  float* out2   = (float*)d_out;                    // Nn*16

  dim3 blk(256);

  // ---- CSR build (radix partition, XCD-local writes) ----
  k_thist<<<dim3(NT), blk, 0, stream>>>(ei, hist, E, NB);
  k_bscan1<<<dim3(NB), blk, 0, stream>>>(hist, off_rel, total, NT, NB);
  k_pscatter<<<dim3(NT), blk, 0, stream>>>(ei, off_rel, total, pairs, E, NB);
  k_bcsr<<<dim3(NB), blk, 0, stream>>>(pairs, total, rowptr, col, Nn, E, NB);

  // ---- layer 1 ----
  k_wcvt<<<dim3((Kp * 64 + 255) / 256), blk, 0, stream>>>(W1, Wb, F, Kp);
  k_gemm1m<<<dim3((Nn + 63) / 64), blk, 0, stream>>>(x, Wb, xwb, Nn, F, nck);
  k_prep1<<<dim3((Nn * 8 + 255) / 256), blk, 0, stream>>>(
      xwb, a_src1, a_dst1, ssrc1, sdst1, Nn);
  k_agg1<<<dim3((Nn * 64 + 255) / 256), blk, 0, stream>>>(
      rowptr, col, ssrc1, sdst1, xwb, b1, h1, Nn);

  // ---- layer 2 ----
  k_gemm2p<<<dim3((Nn * 16 + 255) / 256), blk, 0, stream>>>(
      h1, W2, a_src2, a_dst2, xw2, ssrc2, sdst2, Nn);
  k_agg2<<<dim3((Nn * 64 + 255) / 256), blk, 0, stream>>>(
      rowptr, col, ssrc2, sdst2, xw2, b2, out2, Nn);
}